// Round 10
// baseline (440.466 us; speedup 1.0000x reference)
//
#include <hip/hip_runtime.h>
#include <hip/hip_bf16.h>

using bf16 = __hip_bfloat16;
typedef __attribute__((ext_vector_type(8))) short short8;
typedef __attribute__((ext_vector_type(4))) float f32x4;
typedef __attribute__((ext_vector_type(4))) unsigned short u16x4;

// ---------- helpers ----------
__device__ __forceinline__ void store4(bf16* p, float v0, float v1, float v2, float v3) {
    u16x4 pk;
    bf16 h0 = __float2bfloat16(v0); pk[0] = *(unsigned short*)&h0;
    bf16 h1 = __float2bfloat16(v1); pk[1] = *(unsigned short*)&h1;
    bf16 h2 = __float2bfloat16(v2); pk[2] = *(unsigned short*)&h2;
    bf16 h3 = __float2bfloat16(v3); pk[3] = *(unsigned short*)&h3;
    *(u16x4*)p = pk;
}
__device__ __forceinline__ float b2f(short s) { bf16 h; *(short*)&h = s; return __bfloat162float(h); }

// async global->LDS DMA, 16B per lane. LDS dst is wave-uniform base; HW adds lane*16.
__device__ __forceinline__ void ld_lds16(void* lds, const void* g) {
    __builtin_amdgcn_global_load_lds(
        (const __attribute__((address_space(1))) unsigned int*)g,
        (__attribute__((address_space(3))) unsigned int*)lds,
        16, 0, 0);
}

// Fragment-packed weight index: element (col c, k) stored so one MFMA wf load is
// 64 lanes x 16B CONTIGUOUS. layout: (((c64*(K/32)+ks)*4 + mt)*64 + lane)*8 + j.
__device__ __forceinline__ size_t pidx(int c, int k, int K) {
    return ((size_t)(((c >> 6) * (K >> 5) + (k >> 5)) * 4 + ((c >> 4) & 3)) * 64
            + (((k >> 3) & 3) * 16 + (c & 15))) * 8 + (k & 7);
}

// ---------- consolidated prep: x cast + ALL weight packs + Wbig/bbig + EDGE HIST, ONE launch ----------
// deg_i/cnt2 are zeroed by a preceding hipMemsetAsync (stream-ordered), so the hist
// segment's atomicAdds here are safe.
__global__ __launch_bounds__(256) void prep_all(
    const float* __restrict__ x, bf16* __restrict__ x_b,
    bf16* __restrict__ Wt_sage, const float* __restrict__ sage_Wl, const float* __restrict__ sage_Wr,
    bf16* __restrict__ Wt_fus, const float* __restrict__ fus_W,
    const float* __restrict__ gate_s, const float* __restrict__ gate_a, const float* __restrict__ gate_n,
    bf16* __restrict__ Wt_cat, const float* __restrict__ tvW,
    const float* __restrict__ tskipW, const float* __restrict__ teW,
    bf16* __restrict__ Wgag, const float* __restrict__ gatW,
    float* __restrict__ bvsum, const float* __restrict__ tvb,
    bf16* __restrict__ Wbig, float* __restrict__ bbig,
    const float* __restrict__ Wq, const float* __restrict__ Wk,
    const float* __restrict__ bq, const float* __restrict__ bk,
    const float* __restrict__ attS, const float* __restrict__ attD,
    const int* __restrict__ dst, int* __restrict__ deg_i, int E, int ND)
{
    const int TP = 128 * 128;
    long i = (long)blockIdx.x * 256 + threadIdx.x;
    long nv = ND >> 3;
    if (i < nv) {
        long b = i * 8;
        f32x4 a0 = *(const f32x4*)(x + b);
        f32x4 a1 = *(const f32x4*)(x + b + 4);
        short8 o;
        #pragma unroll
        for (int j = 0; j < 4; ++j) { bf16 h = __float2bfloat16(a0[j]); o[j] = *(short*)&h; }
        #pragma unroll
        for (int j = 0; j < 4; ++j) { bf16 h = __float2bfloat16(a1[j]); o[4 + j] = *(short*)&h; }
        *(short8*)(x_b + b) = o;
        return;
    }
    i -= nv;
    if (i < TP) { int k = (int)i / 128, c = (int)i % 128; Wt_sage[pidx(c, k, 256)] = __float2bfloat16(sage_Wl[i]); return; }
    i -= TP;
    if (i < TP) { int k = (int)i / 128, c = (int)i % 128; Wt_sage[pidx(c, k + 128, 256)] = __float2bfloat16(sage_Wr[i]); return; }
    i -= TP;
    if (i < 3 * TP) {
        int sseg = (int)(i / TP); int r = (int)(i % TP);
        int k = r / 128, c = r % 128;
        const float* g = sseg == 0 ? gate_s : (sseg == 1 ? gate_a : gate_n);
        float gv = 1.0f / (1.0f + expf(-g[0]));
        Wt_fus[pidx(c, sseg * 128 + k, 384)] = __float2bfloat16(fus_W[(size_t)sseg * TP + r] * gv);
        return;
    }
    i -= 3L * TP;
    if (i < 128L * 704) {
        int d = (int)(i / 704), kk = (int)(i % 704);
        float v;
        if (kk < 512)      { int h = kk >> 7, k = kk & 127; v = 0.25f * tvW[k * 512 + h * 128 + d]; }
        else if (kk < 640) { int k = kk - 512;              v = tskipW[k * 128 + d]; }
        else               { int t = kk - 640; int h = t >> 4, j = t & 15; v = 0.25f * teW[j * 512 + h * 128 + d]; }
        Wt_cat[pidx(d, kk, 704)] = __float2bfloat16(v);
        return;
    }
    i -= 128L * 704;
    if (i < 128L * 512) {
        int d = (int)i >> 9, k = (int)i & 511;
        int h = k >> 7, i2 = k & 127;
        Wgag[pidx(d, k, 512)] = __float2bfloat16(0.25f * gatW[(size_t)i2 * 512 + h * 128 + d]);
        return;
    }
    i -= 128L * 512;
    if (i < 128) {
        int d = (int)i;
        bvsum[d] = 0.25f * (tvb[d] + tvb[128 + d] + tvb[256 + d] + tvb[384 + d]);
        return;
    }
    i -= 128;
    if (i < 640L * 128) {
        // composed Wbig [640 cols][128 k] (fragment-packed) + bbig[640]
        int c = (int)(i >> 7), ip = (int)(i & 127);
        float acc = 0.f, bacc = 0.f;
        if (c < 512) {
            int h = c >> 7, i2 = c & 127;
            const float* wkrow = Wk + (size_t)i2 * 512 + h * 128;
            const float* wqrow = Wq + (size_t)ip * 512 + h * 128;
            for (int o = 0; o < 128; ++o) acc += wqrow[o] * wkrow[o];
            if (ip == 0) { const float* bqr = bq + h * 128; for (int o = 0; o < 128; ++o) bacc += bqr[o] * wkrow[o]; }
        } else if (c < 576) {
            int t = c - 512; int h = t >> 4, j = t & 15;
            const float* terow = teW + (size_t)j * 512 + h * 128;
            const float* wqrow = Wq + (size_t)ip * 512 + h * 128;
            for (int o = 0; o < 128; ++o) acc += wqrow[o] * terow[o];
            if (ip == 0) { const float* bqr = bq + h * 128; for (int o = 0; o < 128; ++o) bacc += bqr[o] * terow[o]; }
        } else if (c < 580) {
            int h = c - 576;
            const float* bkr = bk + h * 128;
            const float* wqrow = Wq + (size_t)ip * 512 + h * 128;
            for (int o = 0; o < 128; ++o) acc += wqrow[o] * bkr[o];
            if (ip == 0) { const float* bqr = bq + h * 128; for (int o = 0; o < 128; ++o) bacc += bqr[o] * bkr[o]; }
        } else if (c < 584) {
            int h = c - 580;
            const float* ar = attS + h * 128;
            const float* gr = gatW + (size_t)ip * 512 + h * 128;
            for (int d = 0; d < 128; ++d) acc += gr[d] * ar[d];
        } else if (c < 588) {
            int h = c - 584;
            const float* ar = attD + h * 128;
            const float* gr = gatW + (size_t)ip * 512 + h * 128;
            for (int d = 0; d < 128; ++d) acc += gr[d] * ar[d];
        }
        Wbig[pidx(c, ip, 128)] = __float2bfloat16(acc);
        if (ip == 0) bbig[c] = bacc;
        return;
    }
    i -= 640L * 128;
    // edge histogram (replaces the k_hist dispatch)
    if (i < E) atomicAdd(&deg_i[dst[i]], 1);
}

// ---------- single-block two-pass exclusive scan: deg -> rowptr (replaces scan1/2/3) ----------
__global__ __launch_bounds__(1024) void scan_blk(
    const int* __restrict__ deg, int* __restrict__ rowptr, int N)
{
    __shared__ int psum[1024];
    int t = threadIdx.x;
    int per = (N + 1023) / 1024;
    int base = t * per;
    int s = 0;
    for (int i = 0; i < per; ++i) {
        int idx = base + i;
        s += (idx < N) ? deg[idx] : 0;
    }
    psum[t] = s;
    __syncthreads();
    for (int off = 1; off < 1024; off <<= 1) {
        int add = (t >= off) ? psum[t - off] : 0;
        __syncthreads();
        psum[t] += add;
        __syncthreads();
    }
    int run = psum[t] - s;    // exclusive prefix of this thread's chunk
    for (int i = 0; i < per; ++i) {
        int idx = base + i;
        if (idx < N) { rowptr[idx] = run; run += deg[idx]; }
    }
}

// ---------- gemm_wide + edge scatter fused in one dispatch (independent work) ----------
// Blocks [0, gy): QT GEMM (one block = all 640 cols, depth-2 counted-vmcnt W DMA, proven).
// Blocks [gy, gridDim): grid-stride scatter: pos = rowptr[d] + atomicAdd(&cnt2[d], 1).
__global__ __launch_bounds__(128) void gemm_scatter(
    const bf16* __restrict__ A, const bf16* __restrict__ Wt,
    const float* __restrict__ bias, bf16* __restrict__ C, int n_rows, int ldc,
    const int* __restrict__ src, const int* __restrict__ dst,
    const int* __restrict__ rowptr, int* __restrict__ cnt2,
    int* __restrict__ col_src, int* __restrict__ eidx, int E, int gy)
{
    __shared__ __align__(16) short8 wstg[2][2][4][64];   // [wave][parity][mt][lane] = 16KB
    if (blockIdx.x >= gy) {
        int e0 = (blockIdx.x - gy) * 128 + threadIdx.x;
        int stride = (gridDim.x - gy) * 128;
        for (int e = e0; e < E; e += stride) {
            int d = dst[e];
            int pos = rowptr[d] + atomicAdd(&cnt2[d], 1);
            col_src[pos] = src[e];
            eidx[pos] = e;
        }
        return;
    }
    int row0 = blockIdx.x * 64;
    int wave = threadIdx.x >> 6, lane = threadIdx.x & 63;
    int lrow = lane & 15, quad = lane >> 4;
    short8 xb[4][4];
    #pragma unroll
    for (int ks = 0; ks < 4; ++ks)
        #pragma unroll
        for (int nt = 0; nt < 4; ++nt) {
            int r = row0 + nt * 16 + lrow;
            r = r < n_rows ? r : n_rows - 1;
            xb[ks][nt] = *(const short8*)(A + (size_t)r * 128 + ks * 32 + quad * 8);
        }
    auto issueW = [&](int s, int par) {
        int c64 = (s >> 2) * 2 + wave, ks = s & 3;
        #pragma unroll
        for (int mt = 0; mt < 4; ++mt)
            ld_lds16(&wstg[wave][par][mt][0], Wt + ((size_t)((c64 * 4 + ks) * 4 + mt) * 64 + lane) * 8);
    };
    issueW(0, 0);
    issueW(1, 1);
    for (int cy = 0; cy < 5; ++cy) {
        f32x4 acc[4][4] = {};
        #pragma unroll
        for (int ks = 0; ks < 4; ++ks) {
            int s = cy * 4 + ks, par = s & 1;
            if (s < 18) asm volatile("s_waitcnt vmcnt(4)" ::: "memory");
            else        asm volatile("s_waitcnt vmcnt(0)" ::: "memory");
            short8 wf[4];
            #pragma unroll
            for (int mt = 0; mt < 4; ++mt) wf[mt] = wstg[wave][par][mt][lane];
            asm volatile("s_waitcnt lgkmcnt(0)" ::: "memory");
            if (s + 2 < 20) issueW(s + 2, par);
            __builtin_amdgcn_sched_barrier(0);
            #pragma unroll
            for (int mt = 0; mt < 4; ++mt)
                #pragma unroll
                for (int nt = 0; nt < 4; ++nt)
                    acc[mt][nt] = __builtin_amdgcn_mfma_f32_16x16x32_bf16(wf[mt], xb[ks][nt], acc[mt][nt], 0, 0, 0);
        }
        int cbase = (cy * 2 + wave) * 64;
        #pragma unroll
        for (int nt = 0; nt < 4; ++nt) {
            int row = row0 + nt * 16 + lrow;
            if (row >= n_rows) continue;
            #pragma unroll
            for (int mt = 0; mt < 4; ++mt) {
                int col = cbase + mt * 16 + quad * 4;
                float b0 = bias[col], b1 = bias[col + 1], b2 = bias[col + 2], b3 = bias[col + 3];
                store4(&C[(size_t)row * ldc + col],
                       acc[mt][nt][0] + b0, acc[mt][nt][1] + b1,
                       acc[mt][nt][2] + b2, acc[mt][nt][3] + b3);
            }
        }
    }
}

// ---------- node_fused: SAGE mean + transformer attn + GAT attn, softmax WITHOUT max-shift ----------
#define NCAP 8
__global__ __launch_bounds__(256) void node_fused(
    const bf16* __restrict__ QT, const bf16* __restrict__ x_b,
    const float* __restrict__ edge_attr,
    const int* __restrict__ rowptr, const int* __restrict__ deg_i,
    const int* __restrict__ col_src, const int* __restrict__ eidx,
    bf16* __restrict__ mean_b, bf16* __restrict__ xa, bf16* __restrict__ ga,
    bf16* __restrict__ ea_b, int N)
{
    __shared__ short8 xS[4][NCAP][16];
    __shared__ float eaS[4][NCAP][16];
    __shared__ float wTs[4][NCAP][4];
    __shared__ float wGs[4][NCAP][4];
    int w = threadIdx.x >> 6, l = threadIdx.x & 63;
    int n = blockIdx.x * 4 + w;
    if (n >= N) return;
    int j = l & 15, g4 = l >> 4;
    int p0 = rowptr[n], dg = deg_i[n];
    const float scale = 0.08838834764831845f;
    float qtF[4][8], qeqL[4], qbL[4], adh[4], ashn[4];
    #pragma unroll
    for (int h = 0; h < 4; ++h) {
        short8 q = *(const short8*)(QT + (size_t)n * 640 + h * 128 + j * 8);
        #pragma unroll
        for (int t = 0; t < 8; ++t) qtF[h][t] = b2f(q[t]);
        qeqL[h] = __bfloat162float(QT[(size_t)n * 640 + 512 + h * 16 + j]);
        qbL[h]  = __bfloat162float(QT[(size_t)n * 640 + 576 + h]);
        ashn[h] = __bfloat162float(QT[(size_t)n * 640 + 580 + h]);
        adh[h]  = __bfloat162float(QT[(size_t)n * 640 + 584 + h]);
    }
    float xn0 = __bfloat162float(x_b[(size_t)n * 128 + l]);
    float xn1 = __bfloat162float(x_b[(size_t)n * 128 + l + 64]);
    float s_t[4], s_g[4], xaacc[8] = {}, gaacc[8];
    float mean0 = 0.f, mean1 = 0.f, eaacc = 0.f;
    #pragma unroll
    for (int h = 0; h < 4; ++h) {
        s_t[h] = 0.f;
        float lgs = ashn[h] + adh[h];
        lgs = lgs > 0.f ? lgs : 0.2f * lgs;
        float e = __expf(lgs);
        s_g[h] = e;
        gaacc[h * 2] = e * xn0; gaacc[h * 2 + 1] = e * xn1;
    }
    for (int c0 = 0; c0 < dg; c0 += NCAP) {
        int cc = min(NCAP, dg - c0);
        for (int it = 0; it < ((cc + 3) >> 2); ++it) {
            int i = it * 4 + g4;
            bool valid = i < cc;
            int s = 0;
            short8 xf = {0, 0, 0, 0, 0, 0, 0, 0};
            float ea_j = 0.f;
            if (valid) {
                s = col_src[p0 + c0 + i];
                int eg = eidx[p0 + c0 + i];
                xf = *(const short8*)(x_b + (size_t)s * 128 + j * 8);
                ea_j = edge_attr[(size_t)eg * 16 + j];
                xS[w][i][j] = xf;
                eaS[w][i][j] = ea_j;
            }
            float xv[8];
            #pragma unroll
            for (int t = 0; t < 8; ++t) xv[t] = b2f(xf[t]);
            float p[4];
            #pragma unroll
            for (int h = 0; h < 4; ++h) {
                float a = ea_j * qeqL[h];
                #pragma unroll
                for (int t = 0; t < 8; ++t) a += xv[t] * qtF[h][t];
                p[h] = a;
            }
            #pragma unroll
            for (int off = 1; off < 16; off <<= 1)
                #pragma unroll
                for (int h = 0; h < 4; ++h)
                    p[h] += __shfl_xor(p[h], off, 64);
            if (valid && j == 0) {
                #pragma unroll
                for (int h = 0; h < 4; ++h) {
                    wTs[w][i][h] = __expf((p[h] + qbL[h]) * scale);
                    float as_s = __bfloat162float(QT[(size_t)s * 640 + 580 + h]);
                    float lg = as_s + adh[h];
                    lg = lg > 0.f ? lg : 0.2f * lg;
                    wGs[w][i][h] = __expf(lg);
                }
            }
        }
        for (int i = 0; i < cc; ++i) {
            const bf16* xr = (const bf16*)&xS[w][i][0];
            float xv0 = __bfloat162float(xr[l]);
            float xv1 = __bfloat162float(xr[l + 64]);
            mean0 += xv0; mean1 += xv1;
            #pragma unroll
            for (int h = 0; h < 4; ++h) {
                float at = wTs[w][i][h], ag = wGs[w][i][h];
                s_t[h] += at; s_g[h] += ag;
                xaacc[h * 2] += at * xv0; xaacc[h * 2 + 1] += at * xv1;
                gaacc[h * 2] += ag * xv0; gaacc[h * 2 + 1] += ag * xv1;
            }
            eaacc += wTs[w][i][g4] * eaS[w][i][j];
        }
    }
    float invd = 1.f / fmaxf((float)dg, 1.f);
    mean_b[(size_t)n * 128 + l]      = __float2bfloat16(mean0 * invd);
    mean_b[(size_t)n * 128 + l + 64] = __float2bfloat16(mean1 * invd);
    #pragma unroll
    for (int h = 0; h < 4; ++h) {
        float it = 1.f / (s_t[h] + 1e-16f);
        xa[(size_t)n * 512 + h * 128 + l]      = __float2bfloat16(xaacc[h * 2] * it);
        xa[(size_t)n * 512 + h * 128 + l + 64] = __float2bfloat16(xaacc[h * 2 + 1] * it);
        float ig = 1.f / (s_g[h] + 1e-16f);
        ga[(size_t)n * 512 + h * 128 + l]      = __float2bfloat16(gaacc[h * 2] * ig);
        ga[(size_t)n * 512 + h * 128 + l + 64] = __float2bfloat16(gaacc[h * 2 + 1] * ig);
    }
    ea_b[(size_t)n * 64 + l] = __float2bfloat16(eaacc / (s_t[g4] + 1e-16f));
}

// ---------- fused tail (unchanged, proven ~90 us): depth-2 counted vmcnt DMA ----------
#define STASH(BIASP, USE_BV) do { \
    _Pragma("unroll") \
    for (int nt = 0; nt < 4; ++nt) { \
        int row_l = nt * 16 + lrow; \
        int sw = (row_l & 7) << 4; \
        float bvf = (USE_BV) ? ((deg_i[rA[nt]] > 0) ? 1.f : 0.f) : 0.f; \
        _Pragma("unroll") \
        for (int mt = 0; mt < 4; ++mt) { \
            int col = cbase + mt * 16 + quad * 4; \
            f32x4 bb = *(const f32x4*)((BIASP) + col); \
            u16x4 pk; \
            _Pragma("unroll") \
            for (int jj = 0; jj < 4; ++jj) { \
                float v = acc[mt][nt][jj] + bb[jj]; \
                if (USE_BV) v += bvf * bvsum[col + jj]; \
                bf16 h = __float2bfloat16(fmaxf(v, 0.f)); \
                pk[jj] = *(unsigned short*)&h; \
            } \
            *(u16x4*)(tileb + row_l * 256 + ((col * 2) ^ sw)) = pk; \
        } \
    } \
} while (0)

__global__ __launch_bounds__(128) void tail_fused(
    const bf16* __restrict__ mean_b, const bf16* __restrict__ x_b,
    const bf16* __restrict__ ga, const bf16* __restrict__ xa,
    const bf16* __restrict__ ea_b, const int* __restrict__ deg_i,
    const float* __restrict__ x,
    const bf16* __restrict__ Wt_sage, const bf16* __restrict__ Wgag,
    const bf16* __restrict__ Wt_cat, const bf16* __restrict__ Wt_fus,
    const float* __restrict__ sage_b, const float* __restrict__ gat_bias,
    const float* __restrict__ tskip_b, const float* __restrict__ bvsum,
    const float* __restrict__ fus_b, const float* __restrict__ fus_g,
    const float* __restrict__ fus_beta, const float* __restrict__ norm_g,
    const float* __restrict__ norm_b,
    float* __restrict__ out, int N)
{
    __shared__ __align__(16) char tileb[64 * 256];
    __shared__ __align__(16) short8 stg[2][2][8][64];
    __shared__ float2 st1[2][64];
    __shared__ float2 st2[2][64];
    int wave = threadIdx.x >> 6, lane = threadIdx.x & 63;
    int lrow = lane & 15, quad = lane >> 4;
    int kq = quad * 8;
    int row0 = blockIdx.x * 64;
    int cbase = wave * 64;
    int rA[4];
    #pragma unroll
    for (int t = 0; t < 4; ++t) {
        int r = row0 + t * 16 + lrow;
        rA[t] = r < N ? r : N - 1;
    }
    f32x4 facc[4][4] = {};

    auto issueA = [&](const bf16* base, int ldA, int kA, int par) {
        #pragma unroll
        for (int t = 0; t < 4; ++t)
            ld_lds16(&stg[wave][par][t][0], base + (size_t)rA[t] * ldA + kA);
    };
    auto issueW = [&](const bf16* Wt, int stepIdx, int par) {
        #pragma unroll
        for (int mt = 0; mt < 4; ++mt)
            ld_lds16(&stg[wave][par][4 + mt][0], Wt + ((size_t)(stepIdx * 4 + mt) * 64 + lane) * 8);
    };
    auto mfstep = [&](f32x4 (&acc)[4][4], int par) {
        short8 xf[4], wf[4];
        #pragma unroll
        for (int t = 0; t < 4; ++t) { xf[t] = stg[wave][par][t][lane]; wf[t] = stg[wave][par][4 + t][lane]; }
        #pragma unroll
        for (int mt = 0; mt < 4; ++mt)
            #pragma unroll
            for (int nt = 0; nt < 4; ++nt)
                acc[mt][nt] = __builtin_amdgcn_mfma_f32_16x16x32_bf16(wf[mt], xf[nt], acc[mt][nt], 0, 0, 0);
    };
    auto fuse_seg = [&](int SEG) {
        issueW(Wt_fus, wave * 12 + SEG * 4, 0);
        issueW(Wt_fus, wave * 12 + SEG * 4 + 1, 1);
        #pragma unroll
        for (int ks = 0; ks < 4; ++ks) {
            int cur = ks & 1;
            if (ks < 3) asm volatile("s_waitcnt vmcnt(4)" ::: "memory");
            else        asm volatile("s_waitcnt vmcnt(0)" ::: "memory");
            int kT = ks * 32 + kq;
            short8 xf[4], wf[4];
            #pragma unroll
            for (int t = 0; t < 4; ++t) {
                int row_l = t * 16 + lrow;
                xf[t] = *(const short8*)(tileb + row_l * 256 + ((kT * 2) ^ ((row_l & 7) << 4)));
            }
            #pragma unroll
            for (int mt = 0; mt < 4; ++mt) wf[mt] = stg[wave][cur][4 + mt][lane];
            #pragma unroll
            for (int mt = 0; mt < 4; ++mt)
                #pragma unroll
                for (int nt = 0; nt < 4; ++nt)
                    facc[mt][nt] = __builtin_amdgcn_mfma_f32_16x16x32_bf16(wf[mt], xf[nt], facc[mt][nt], 0, 0, 0);
            if (ks + 2 < 4) {
                asm volatile("s_waitcnt lgkmcnt(0)" ::: "memory");
                issueW(Wt_fus, wave * 12 + SEG * 4 + ks + 2, cur);
            }
        }
    };

    // ===== branch 1: SAGE  (K=256: mean_b | x_b, NS=8) =====
    {
        f32x4 acc[4][4] = {};
        issueA(mean_b, 128, kq, 0);
        issueW(Wt_sage, wave * 8, 0);
        issueA(mean_b, 128, 32 + kq, 1);
        issueW(Wt_sage, wave * 8 + 1, 1);
        #pragma unroll
        for (int ks = 0; ks < 8; ++ks) {
            int cur = ks & 1;
            if (ks < 7) asm volatile("s_waitcnt vmcnt(8)" ::: "memory");
            else        asm volatile("s_waitcnt vmcnt(0)" ::: "memory");
            mfstep(acc, cur);
            if (ks + 2 < 8) {
                asm volatile("s_waitcnt lgkmcnt(0)" ::: "memory");
                int p = ks + 2;
                issueA((p < 4) ? mean_b : x_b, 128, (p & 3) * 32 + kq, cur);
                issueW(Wt_sage, wave * 8 + p, cur);
            }
        }
        STASH(sage_b, 0);
    }
    __syncthreads();
    fuse_seg(0);
    __syncthreads();

    // ===== branch 2: cat  (K=704: xa | x_b | ea_b, NS=22) =====
    {
        f32x4 acc[4][4] = {};
        issueA(xa, 512, kq, 0);
        issueW(Wt_cat, wave * 22, 0);
        issueA(xa, 512, 32 + kq, 1);
        issueW(Wt_cat, wave * 22 + 1, 1);
        #pragma unroll
        for (int ks = 0; ks < 22; ++ks) {
            int cur = ks & 1;
            if (ks < 21) asm volatile("s_waitcnt vmcnt(8)" ::: "memory");
            else         asm volatile("s_waitcnt vmcnt(0)" ::: "memory");
            mfstep(acc, cur);
            if (ks + 2 < 22) {
                asm volatile("s_waitcnt lgkmcnt(0)" ::: "memory");
                int p = ks + 2;
                if (p < 16)      issueA(xa,   512, p * 32 + kq,        cur);
                else if (p < 20) issueA(x_b,  128, (p - 16) * 32 + kq, cur);
                else             issueA(ea_b,  64, (p - 20) * 32 + kq, cur);
                issueW(Wt_cat, wave * 22 + p, cur);
            }
        }
        STASH(tskip_b, 1);
    }
    __syncthreads();
    fuse_seg(1);
    __syncthreads();

    // ===== branch 3: GAT  (K=512: ga, NS=16) =====
    {
        f32x4 acc[4][4] = {};
        issueA(ga, 512, kq, 0);
        issueW(Wgag, wave * 16, 0);
        issueA(ga, 512, 32 + kq, 1);
        issueW(Wgag, wave * 16 + 1, 1);
        #pragma unroll
        for (int ks = 0; ks < 16; ++ks) {
            int cur = ks & 1;
            if (ks < 15) asm volatile("s_waitcnt vmcnt(8)" ::: "memory");
            else         asm volatile("s_waitcnt vmcnt(0)" ::: "memory");
            mfstep(acc, cur);
            if (ks + 2 < 16) {
                asm volatile("s_waitcnt lgkmcnt(0)" ::: "memory");
                int p = ks + 2;
                issueA(ga, 512, p * 32 + kq, cur);
                issueW(Wgag, wave * 16 + p, cur);
            }
        }
        STASH(gat_bias, 0);
    }
    __syncthreads();
    fuse_seg(2);

    // ===== epilogue: +fus_b -> LN1 -> relu -> +x -> LN2 -> out =====
    #pragma unroll
    for (int nt = 0; nt < 4; ++nt) {
        float s = 0.f, q = 0.f;
        #pragma unroll
        for (int mt = 0; mt < 4; ++mt) {
            int col = cbase + mt * 16 + quad * 4;
            f32x4 bb = *(const f32x4*)(fus_b + col);
            #pragma unroll
            for (int jj = 0; jj < 4; ++jj) {
                float v = facc[mt][nt][jj] + bb[jj];
                facc[mt][nt][jj] = v;
                s += v; q += v * v;
            }
        }
        s += __shfl_xor(s, 16, 64); q += __shfl_xor(q, 16, 64);
        s += __shfl_xor(s, 32, 64); q += __shfl_xor(q, 32, 64);
        if (quad == 0) st1[wave][nt * 16 + lrow] = make_float2(s, q);
    }
    __syncthreads();
    float m1[4], inv1[4];
    #pragma unroll
    for (int nt = 0; nt < 4; ++nt) {
        float2 a = st1[0][nt * 16 + lrow], b = st1[1][nt * 16 + lrow];
        float S = a.x + b.x, Q = a.y + b.y;
        float m = S * (1.f / 128.f);
        m1[nt] = m;
        inv1[nt] = rsqrtf(Q * (1.f / 128.f) - m * m + 1e-5f);
    }
    #pragma unroll
    for (int nt = 0; nt < 4; ++nt) {
        float s = 0.f, q = 0.f;
        #pragma unroll
        for (int mt = 0; mt < 4; ++mt) {
            int col = cbase + mt * 16 + quad * 4;
            f32x4 gv = *(const f32x4*)(fus_g + col);
            f32x4 bv = *(const f32x4*)(fus_beta + col);
            f32x4 xv = *(const f32x4*)(x + (size_t)rA[nt] * 128 + col);
            #pragma unroll
            for (int jj = 0; jj < 4; ++jj) {
                float y = fmaxf((facc[mt][nt][jj] - m1[nt]) * inv1[nt] * gv[jj] + bv[jj], 0.f);
                float z = xv[jj] + y;
                facc[mt][nt][jj] = z;
                s += z; q += z * z;
            }
        }
        s += __shfl_xor(s, 16, 64); q += __shfl_xor(q, 16, 64);
        s += __shfl_xor(s, 32, 64); q += __shfl_xor(q, 32, 64);
        if (quad == 0) st2[wave][nt * 16 + lrow] = make_float2(s, q);
    }
    __syncthreads();
    #pragma unroll
    for (int nt = 0; nt < 4; ++nt) {
        int row = row0 + nt * 16 + lrow;
        if (row >= N) continue;
        float2 a = st2[0][nt * 16 + lrow], b = st2[1][nt * 16 + lrow];
        float S = a.x + b.x, Q = a.y + b.y;
        float m = S * (1.f / 128.f);
        float inv = rsqrtf(Q * (1.f / 128.f) - m * m + 1e-5f);
        #pragma unroll
        for (int mt = 0; mt < 4; ++mt) {
            int col = cbase + mt * 16 + quad * 4;
            f32x4 ngv = *(const f32x4*)(norm_g + col);
            f32x4 nbv = *(const f32x4*)(norm_b + col);
            f32x4 o;
            #pragma unroll
            for (int jj = 0; jj < 4; ++jj)
                o[jj] = (facc[mt][nt][jj] - m) * inv * ngv[jj] + nbv[jj];
            *(f32x4*)(out + (size_t)row * 128 + col) = o;
        }
    }
}

extern "C" void kernel_launch(void* const* d_in, const int* in_sizes, int n_in,
                              void* d_out, int out_size, void* d_ws, size_t ws_size,
                              hipStream_t stream)
{
    const float* x        = (const float*)d_in[0];
    const int*   ei       = (const int*)d_in[1];
    const float* edge_attr= (const float*)d_in[2];
    const float* sage_Wl  = (const float*)d_in[3];
    const float* sage_Wr  = (const float*)d_in[4];
    const float* sage_b   = (const float*)d_in[5];
    const float* tq_W     = (const float*)d_in[6];
    const float* tq_b     = (const float*)d_in[7];
    const float* tk_W     = (const float*)d_in[8];
    const float* tk_b     = (const float*)d_in[9];
    const float* tv_W     = (const float*)d_in[10];
    const float* tv_b     = (const float*)d_in[11];
    const float* te_W     = (const float*)d_in[12];
    const float* tskip_W  = (const float*)d_in[13];
    const float* tskip_b  = (const float*)d_in[14];
    const float* gat_W    = (const float*)d_in[15];
    const float* att_s_w  = (const float*)d_in[16];
    const float* att_d_w  = (const float*)d_in[17];
    const float* gat_bias = (const float*)d_in[18];
    const float* gate_s   = (const float*)d_in[19];
    const float* gate_a   = (const float*)d_in[20];
    const float* gate_n   = (const float*)d_in[21];
    const float* fus_W    = (const float*)d_in[22];
    const float* fus_b    = (const float*)d_in[23];
    const float* fus_g    = (const float*)d_in[24];
    const float* fus_beta = (const float*)d_in[25];
    const float* norm_g   = (const float*)d_in[26];
    const float* norm_b   = (const float*)d_in[27];

    int N = in_sizes[0] / 128;
    int E = in_sizes[2] / 16;
    const int* src = ei;
    const int* dst = ei + E;
    int ND = N * 128;

    // ---- workspace ----
    char* wsb = (char*)d_ws;
    size_t off = 0;
    auto carve = [&](size_t bytes) -> char* {
        char* p = wsb + off;
        off += (bytes + 255) & ~(size_t)255;
        return p;
    };
    int*   deg_i   = (int*)carve((size_t)N * 4);          // zeroed by memset below
    int*   cnt2    = (int*)carve((size_t)N * 4);          // zeroed by memset below
    size_t zero_bytes = off;
    int*   rowptr  = (int*)carve((size_t)N * 4);
    int*   col_src = (int*)carve((size_t)E * 4);
    int*   eidx    = (int*)carve((size_t)E * 4);
    bf16*  x_b     = (bf16*)carve((size_t)N * 128 * 2);
    bf16*  QT      = (bf16*)carve((size_t)N * 640 * 2);
    bf16*  xa      = (bf16*)carve((size_t)N * 512 * 2);
    bf16*  ga      = (bf16*)carve((size_t)N * 512 * 2);
    bf16*  mean_b  = (bf16*)carve((size_t)N * 128 * 2);
    bf16*  ea_b    = (bf16*)carve((size_t)N * 64 * 2);
    bf16*  Wbig    = (bf16*)carve((size_t)640 * 128 * 2);
    float* bbig    = (float*)carve((size_t)640 * 4);
    bf16*  Wt_sage = (bf16*)carve((size_t)128 * 256 * 2);
    bf16*  Wt_fus  = (bf16*)carve((size_t)128 * 384 * 2);
    bf16*  Wt_cat  = (bf16*)carve((size_t)128 * 704 * 2);
    bf16*  Wgag    = (bf16*)carve((size_t)128 * 512 * 2);
    float* bvsum   = (float*)carve((size_t)128 * 4);

    // 0) zero deg_i + cnt2 via async memset (stream-ordered, graph-capturable)
    hipMemsetAsync(wsb, 0, zero_bytes, stream);

    // 1) prep: x cast + ALL weight packs + Wbig/bbig + edge hist in ONE launch
    const long TP = 128 * 128;
    long prep_total = (long)(ND >> 3) + 5L * TP + 128L * 704 + 128L * 512 + 128
                    + 640L * 128 + (long)E;
    int prep_blocks = (int)((prep_total + 255) / 256);
    prep_all<<<prep_blocks, 256, 0, stream>>>(
        x, x_b, Wt_sage, sage_Wl, sage_Wr, Wt_fus, fus_W, gate_s, gate_a, gate_n,
        Wt_cat, tv_W, tskip_W, te_W, Wgag, gat_W, bvsum, tv_b,
        Wbig, bbig, tq_W, tk_W, tq_b, tk_b, att_s_w, att_d_w,
        dst, deg_i, E, ND);

    // 2) exclusive scan deg -> rowptr (ONE block, replaces scan1/2/3)
    scan_blk<<<1, 1024, 0, stream>>>(deg_i, rowptr, N);

    int gy64 = (N + 63) / 64, gnode = (N + 3) / 4;

    // 3) QT GEMM + edge scatter fused (independent work, one dispatch)
    gemm_scatter<<<gy64 + 256, 128, 0, stream>>>(
        x_b, Wbig, bbig, QT, N, 640,
        src, dst, rowptr, cnt2, col_src, eidx, E, gy64);

    // 4) the one per-edge kernel
    node_fused<<<gnode, 256, 0, stream>>>(QT, x_b, edge_attr, rowptr, deg_i, col_src, eidx,
                                          mean_b, xa, ga, ea_b, N);

    // 5) everything downstream of node_fused in ONE kernel (unchanged, proven)
    tail_fused<<<gy64, 128, 0, stream>>>(
        mean_b, x_b, ga, xa, ea_b, deg_i, x,
        Wt_sage, Wgag, Wt_cat, Wt_fus,
        sage_b, gat_bias, tskip_b, bvsum,
        fus_b, fus_g, fus_beta, norm_g, norm_b,
        (float*)d_out, N);
}

// Round 11
// 361.037 us; speedup vs baseline: 1.2200x; 1.2200x over previous
//
#include <hip/hip_runtime.h>
#include <hip/hip_bf16.h>

using bf16 = __hip_bfloat16;
typedef __attribute__((ext_vector_type(8))) short short8;
typedef __attribute__((ext_vector_type(4))) float f32x4;
typedef __attribute__((ext_vector_type(4))) unsigned short u16x4;

// ---------- helpers ----------
__device__ __forceinline__ void store4(bf16* p, float v0, float v1, float v2, float v3) {
    u16x4 pk;
    bf16 h0 = __float2bfloat16(v0); pk[0] = *(unsigned short*)&h0;
    bf16 h1 = __float2bfloat16(v1); pk[1] = *(unsigned short*)&h1;
    bf16 h2 = __float2bfloat16(v2); pk[2] = *(unsigned short*)&h2;
    bf16 h3 = __float2bfloat16(v3); pk[3] = *(unsigned short*)&h3;
    *(u16x4*)p = pk;
}
__device__ __forceinline__ float b2f(short s) { bf16 h; *(short*)&h = s; return __bfloat162float(h); }

// async global->LDS DMA, 16B per lane. LDS dst is wave-uniform base; HW adds lane*16.
__device__ __forceinline__ void ld_lds16(void* lds, const void* g) {
    __builtin_amdgcn_global_load_lds(
        (const __attribute__((address_space(1))) unsigned int*)g,
        (__attribute__((address_space(3))) unsigned int*)lds,
        16, 0, 0);
}

// Fragment-packed weight index: element (col c, k) stored so one MFMA wf load is
// 64 lanes x 16B CONTIGUOUS. layout: (((c64*(K/32)+ks)*4 + mt)*64 + lane)*8 + j.
__device__ __forceinline__ size_t pidx(int c, int k, int K) {
    return ((size_t)(((c >> 6) * (K >> 5) + (k >> 5)) * 4 + ((c >> 4) & 3)) * 64
            + (((k >> 3) & 3) * 16 + (c & 15))) * 8 + (k & 7);
}

// ---------- consolidated prep: x cast + ALL weight packs + Wbig/bbig + EDGE HIST, ONE launch ----------
// deg_i/cnt2 are zeroed by a preceding hipMemsetAsync (stream-ordered), so the hist
// segment's atomicAdds here are safe.
__global__ __launch_bounds__(256) void prep_all(
    const float* __restrict__ x, bf16* __restrict__ x_b,
    bf16* __restrict__ Wt_sage, const float* __restrict__ sage_Wl, const float* __restrict__ sage_Wr,
    bf16* __restrict__ Wt_fus, const float* __restrict__ fus_W,
    const float* __restrict__ gate_s, const float* __restrict__ gate_a, const float* __restrict__ gate_n,
    bf16* __restrict__ Wt_cat, const float* __restrict__ tvW,
    const float* __restrict__ tskipW, const float* __restrict__ teW,
    bf16* __restrict__ Wgag, const float* __restrict__ gatW,
    float* __restrict__ bvsum, const float* __restrict__ tvb,
    bf16* __restrict__ Wbig, float* __restrict__ bbig,
    const float* __restrict__ Wq, const float* __restrict__ Wk,
    const float* __restrict__ bq, const float* __restrict__ bk,
    const float* __restrict__ attS, const float* __restrict__ attD,
    const int* __restrict__ dst, int* __restrict__ deg_i, int E, int ND)
{
    const int TP = 128 * 128;
    long i = (long)blockIdx.x * 256 + threadIdx.x;
    long nv = ND >> 3;
    if (i < nv) {
        long b = i * 8;
        f32x4 a0 = *(const f32x4*)(x + b);
        f32x4 a1 = *(const f32x4*)(x + b + 4);
        short8 o;
        #pragma unroll
        for (int j = 0; j < 4; ++j) { bf16 h = __float2bfloat16(a0[j]); o[j] = *(short*)&h; }
        #pragma unroll
        for (int j = 0; j < 4; ++j) { bf16 h = __float2bfloat16(a1[j]); o[4 + j] = *(short*)&h; }
        *(short8*)(x_b + b) = o;
        return;
    }
    i -= nv;
    if (i < TP) { int k = (int)i / 128, c = (int)i % 128; Wt_sage[pidx(c, k, 256)] = __float2bfloat16(sage_Wl[i]); return; }
    i -= TP;
    if (i < TP) { int k = (int)i / 128, c = (int)i % 128; Wt_sage[pidx(c, k + 128, 256)] = __float2bfloat16(sage_Wr[i]); return; }
    i -= TP;
    if (i < 3 * TP) {
        int sseg = (int)(i / TP); int r = (int)(i % TP);
        int k = r / 128, c = r % 128;
        const float* g = sseg == 0 ? gate_s : (sseg == 1 ? gate_a : gate_n);
        float gv = 1.0f / (1.0f + expf(-g[0]));
        Wt_fus[pidx(c, sseg * 128 + k, 384)] = __float2bfloat16(fus_W[(size_t)sseg * TP + r] * gv);
        return;
    }
    i -= 3L * TP;
    if (i < 128L * 704) {
        int d = (int)(i / 704), kk = (int)(i % 704);
        float v;
        if (kk < 512)      { int h = kk >> 7, k = kk & 127; v = 0.25f * tvW[k * 512 + h * 128 + d]; }
        else if (kk < 640) { int k = kk - 512;              v = tskipW[k * 128 + d]; }
        else               { int t = kk - 640; int h = t >> 4, j = t & 15; v = 0.25f * teW[j * 512 + h * 128 + d]; }
        Wt_cat[pidx(d, kk, 704)] = __float2bfloat16(v);
        return;
    }
    i -= 128L * 704;
    if (i < 128L * 512) {
        int d = (int)i >> 9, k = (int)i & 511;
        int h = k >> 7, i2 = k & 127;
        Wgag[pidx(d, k, 512)] = __float2bfloat16(0.25f * gatW[(size_t)i2 * 512 + h * 128 + d]);
        return;
    }
    i -= 128L * 512;
    if (i < 128) {
        int d = (int)i;
        bvsum[d] = 0.25f * (tvb[d] + tvb[128 + d] + tvb[256 + d] + tvb[384 + d]);
        return;
    }
    i -= 128;
    if (i < 640L * 128) {
        // composed Wbig [640 cols][128 k] (fragment-packed) + bbig[640]
        int c = (int)(i >> 7), ip = (int)(i & 127);
        float acc = 0.f, bacc = 0.f;
        if (c < 512) {
            int h = c >> 7, i2 = c & 127;
            const float* wkrow = Wk + (size_t)i2 * 512 + h * 128;
            const float* wqrow = Wq + (size_t)ip * 512 + h * 128;
            for (int o = 0; o < 128; ++o) acc += wqrow[o] * wkrow[o];
            if (ip == 0) { const float* bqr = bq + h * 128; for (int o = 0; o < 128; ++o) bacc += bqr[o] * wkrow[o]; }
        } else if (c < 576) {
            int t = c - 512; int h = t >> 4, j = t & 15;
            const float* terow = teW + (size_t)j * 512 + h * 128;
            const float* wqrow = Wq + (size_t)ip * 512 + h * 128;
            for (int o = 0; o < 128; ++o) acc += wqrow[o] * terow[o];
            if (ip == 0) { const float* bqr = bq + h * 128; for (int o = 0; o < 128; ++o) bacc += bqr[o] * terow[o]; }
        } else if (c < 580) {
            int h = c - 576;
            const float* bkr = bk + h * 128;
            const float* wqrow = Wq + (size_t)ip * 512 + h * 128;
            for (int o = 0; o < 128; ++o) acc += wqrow[o] * bkr[o];
            if (ip == 0) { const float* bqr = bq + h * 128; for (int o = 0; o < 128; ++o) bacc += bqr[o] * bkr[o]; }
        } else if (c < 584) {
            int h = c - 580;
            const float* ar = attS + h * 128;
            const float* gr = gatW + (size_t)ip * 512 + h * 128;
            for (int d = 0; d < 128; ++d) acc += gr[d] * ar[d];
        } else if (c < 588) {
            int h = c - 584;
            const float* ar = attD + h * 128;
            const float* gr = gatW + (size_t)ip * 512 + h * 128;
            for (int d = 0; d < 128; ++d) acc += gr[d] * ar[d];
        }
        Wbig[pidx(c, ip, 128)] = __float2bfloat16(acc);
        if (ip == 0) bbig[c] = bacc;
        return;
    }
    i -= 640L * 128;
    // edge histogram (replaces the k_hist dispatch)
    if (i < E) atomicAdd(&deg_i[dst[i]], 1);
}

// ---------- scan stage 1: per-block exclusive prefix (loc) + block sums (partial) ----------
__global__ __launch_bounds__(256) void k_scan1(
    const int* __restrict__ deg_i, int* __restrict__ loc, int* __restrict__ partial, int N)
{
    __shared__ int sm[256];
    int t = threadIdx.x, i = blockIdx.x * 256 + t;
    int v = (i < N) ? deg_i[i] : 0;
    sm[t] = v;
    __syncthreads();
    for (int off = 1; off < 256; off <<= 1) {
        int add = (t >= off) ? sm[t - off] : 0;
        __syncthreads();
        sm[t] += add;
        __syncthreads();
    }
    if (i < N) loc[i] = sm[t] - v;
    if (t == 255) partial[blockIdx.x] = sm[255];
}

// ---------- scan stage 2: exclusive scan of block sums (carry loop handles any nb) ----------
__global__ __launch_bounds__(256) void k_scan2(int* __restrict__ partial, int nb) {
    __shared__ int sm[256];
    int t = threadIdx.x;
    int carry = 0;
    for (int base = 0; base < nb; base += 256) {
        int idx = base + t;
        int v = (idx < nb) ? partial[idx] : 0;
        sm[t] = v;
        __syncthreads();
        for (int off = 1; off < 256; off <<= 1) {
            int add = (t >= off) ? sm[t - off] : 0;
            __syncthreads();
            sm[t] += add;
            __syncthreads();
        }
        if (idx < nb) partial[idx] = carry + sm[t] - v;
        int tot = sm[255];
        __syncthreads();
        carry += tot;
    }
}
// NOTE: scan3 is GONE -- consumers compute rowptr on the fly: loc[d] + partial[d>>8].

// ---------- gemm_wide + edge scatter fused in one dispatch (independent work) ----------
// Blocks [0, gy): QT GEMM (one block = all 640 cols, depth-2 counted-vmcnt W DMA, proven).
// Blocks [gy, gridDim): grid-stride scatter: pos = loc[d]+partial[d>>8]+atomicAdd(&cnt2[d],1).
__global__ __launch_bounds__(128) void gemm_scatter(
    const bf16* __restrict__ A, const bf16* __restrict__ Wt,
    const float* __restrict__ bias, bf16* __restrict__ C, int n_rows, int ldc,
    const int* __restrict__ src, const int* __restrict__ dst,
    const int* __restrict__ loc, const int* __restrict__ partial, int* __restrict__ cnt2,
    int* __restrict__ col_src, int* __restrict__ eidx, int E, int gy)
{
    __shared__ __align__(16) short8 wstg[2][2][4][64];   // [wave][parity][mt][lane] = 16KB
    if (blockIdx.x >= gy) {
        int e0 = (blockIdx.x - gy) * 128 + threadIdx.x;
        int stride = (gridDim.x - gy) * 128;
        for (int e = e0; e < E; e += stride) {
            int d = dst[e];
            int pos = loc[d] + partial[d >> 8] + atomicAdd(&cnt2[d], 1);
            col_src[pos] = src[e];
            eidx[pos] = e;
        }
        return;
    }
    int row0 = blockIdx.x * 64;
    int wave = threadIdx.x >> 6, lane = threadIdx.x & 63;
    int lrow = lane & 15, quad = lane >> 4;
    short8 xb[4][4];
    #pragma unroll
    for (int ks = 0; ks < 4; ++ks)
        #pragma unroll
        for (int nt = 0; nt < 4; ++nt) {
            int r = row0 + nt * 16 + lrow;
            r = r < n_rows ? r : n_rows - 1;
            xb[ks][nt] = *(const short8*)(A + (size_t)r * 128 + ks * 32 + quad * 8);
        }
    auto issueW = [&](int s, int par) {
        int c64 = (s >> 2) * 2 + wave, ks = s & 3;
        #pragma unroll
        for (int mt = 0; mt < 4; ++mt)
            ld_lds16(&wstg[wave][par][mt][0], Wt + ((size_t)((c64 * 4 + ks) * 4 + mt) * 64 + lane) * 8);
    };
    issueW(0, 0);
    issueW(1, 1);
    for (int cy = 0; cy < 5; ++cy) {
        f32x4 acc[4][4] = {};
        #pragma unroll
        for (int ks = 0; ks < 4; ++ks) {
            int s = cy * 4 + ks, par = s & 1;
            if (s < 18) asm volatile("s_waitcnt vmcnt(4)" ::: "memory");
            else        asm volatile("s_waitcnt vmcnt(0)" ::: "memory");
            short8 wf[4];
            #pragma unroll
            for (int mt = 0; mt < 4; ++mt) wf[mt] = wstg[wave][par][mt][lane];
            asm volatile("s_waitcnt lgkmcnt(0)" ::: "memory");
            if (s + 2 < 20) issueW(s + 2, par);
            __builtin_amdgcn_sched_barrier(0);
            #pragma unroll
            for (int mt = 0; mt < 4; ++mt)
                #pragma unroll
                for (int nt = 0; nt < 4; ++nt)
                    acc[mt][nt] = __builtin_amdgcn_mfma_f32_16x16x32_bf16(wf[mt], xb[ks][nt], acc[mt][nt], 0, 0, 0);
        }
        int cbase = (cy * 2 + wave) * 64;
        #pragma unroll
        for (int nt = 0; nt < 4; ++nt) {
            int row = row0 + nt * 16 + lrow;
            if (row >= n_rows) continue;
            #pragma unroll
            for (int mt = 0; mt < 4; ++mt) {
                int col = cbase + mt * 16 + quad * 4;
                float b0 = bias[col], b1 = bias[col + 1], b2 = bias[col + 2], b3 = bias[col + 3];
                store4(&C[(size_t)row * ldc + col],
                       acc[mt][nt][0] + b0, acc[mt][nt][1] + b1,
                       acc[mt][nt][2] + b2, acc[mt][nt][3] + b3);
            }
        }
    }
}

// ---------- node_fused: SAGE mean + transformer attn + GAT attn, softmax WITHOUT max-shift ----------
#define NCAP 8
__global__ __launch_bounds__(256) void node_fused(
    const bf16* __restrict__ QT, const bf16* __restrict__ x_b,
    const float* __restrict__ edge_attr,
    const int* __restrict__ loc, const int* __restrict__ partial,
    const int* __restrict__ deg_i,
    const int* __restrict__ col_src, const int* __restrict__ eidx,
    bf16* __restrict__ mean_b, bf16* __restrict__ xa, bf16* __restrict__ ga,
    bf16* __restrict__ ea_b, int N)
{
    __shared__ short8 xS[4][NCAP][16];
    __shared__ float eaS[4][NCAP][16];
    __shared__ float wTs[4][NCAP][4];
    __shared__ float wGs[4][NCAP][4];
    int w = threadIdx.x >> 6, l = threadIdx.x & 63;
    int n = blockIdx.x * 4 + w;
    if (n >= N) return;
    int j = l & 15, g4 = l >> 4;
    int p0 = loc[n] + partial[n >> 8], dg = deg_i[n];
    const float scale = 0.08838834764831845f;
    float qtF[4][8], qeqL[4], qbL[4], adh[4], ashn[4];
    #pragma unroll
    for (int h = 0; h < 4; ++h) {
        short8 q = *(const short8*)(QT + (size_t)n * 640 + h * 128 + j * 8);
        #pragma unroll
        for (int t = 0; t < 8; ++t) qtF[h][t] = b2f(q[t]);
        qeqL[h] = __bfloat162float(QT[(size_t)n * 640 + 512 + h * 16 + j]);
        qbL[h]  = __bfloat162float(QT[(size_t)n * 640 + 576 + h]);
        ashn[h] = __bfloat162float(QT[(size_t)n * 640 + 580 + h]);
        adh[h]  = __bfloat162float(QT[(size_t)n * 640 + 584 + h]);
    }
    float xn0 = __bfloat162float(x_b[(size_t)n * 128 + l]);
    float xn1 = __bfloat162float(x_b[(size_t)n * 128 + l + 64]);
    float s_t[4], s_g[4], xaacc[8] = {}, gaacc[8];
    float mean0 = 0.f, mean1 = 0.f, eaacc = 0.f;
    #pragma unroll
    for (int h = 0; h < 4; ++h) {
        s_t[h] = 0.f;
        float lgs = ashn[h] + adh[h];
        lgs = lgs > 0.f ? lgs : 0.2f * lgs;
        float e = __expf(lgs);
        s_g[h] = e;
        gaacc[h * 2] = e * xn0; gaacc[h * 2 + 1] = e * xn1;
    }
    for (int c0 = 0; c0 < dg; c0 += NCAP) {
        int cc = min(NCAP, dg - c0);
        for (int it = 0; it < ((cc + 3) >> 2); ++it) {
            int i = it * 4 + g4;
            bool valid = i < cc;
            int s = 0;
            short8 xf = {0, 0, 0, 0, 0, 0, 0, 0};
            float ea_j = 0.f;
            if (valid) {
                s = col_src[p0 + c0 + i];
                int eg = eidx[p0 + c0 + i];
                xf = *(const short8*)(x_b + (size_t)s * 128 + j * 8);
                ea_j = edge_attr[(size_t)eg * 16 + j];
                xS[w][i][j] = xf;
                eaS[w][i][j] = ea_j;
            }
            float xv[8];
            #pragma unroll
            for (int t = 0; t < 8; ++t) xv[t] = b2f(xf[t]);
            float p[4];
            #pragma unroll
            for (int h = 0; h < 4; ++h) {
                float a = ea_j * qeqL[h];
                #pragma unroll
                for (int t = 0; t < 8; ++t) a += xv[t] * qtF[h][t];
                p[h] = a;
            }
            #pragma unroll
            for (int off = 1; off < 16; off <<= 1)
                #pragma unroll
                for (int h = 0; h < 4; ++h)
                    p[h] += __shfl_xor(p[h], off, 64);
            if (valid && j == 0) {
                #pragma unroll
                for (int h = 0; h < 4; ++h) {
                    wTs[w][i][h] = __expf((p[h] + qbL[h]) * scale);
                    float as_s = __bfloat162float(QT[(size_t)s * 640 + 580 + h]);
                    float lg = as_s + adh[h];
                    lg = lg > 0.f ? lg : 0.2f * lg;
                    wGs[w][i][h] = __expf(lg);
                }
            }
        }
        for (int i = 0; i < cc; ++i) {
            const bf16* xr = (const bf16*)&xS[w][i][0];
            float xv0 = __bfloat162float(xr[l]);
            float xv1 = __bfloat162float(xr[l + 64]);
            mean0 += xv0; mean1 += xv1;
            #pragma unroll
            for (int h = 0; h < 4; ++h) {
                float at = wTs[w][i][h], ag = wGs[w][i][h];
                s_t[h] += at; s_g[h] += ag;
                xaacc[h * 2] += at * xv0; xaacc[h * 2 + 1] += at * xv1;
                gaacc[h * 2] += ag * xv0; gaacc[h * 2 + 1] += ag * xv1;
            }
            eaacc += wTs[w][i][g4] * eaS[w][i][j];
        }
    }
    float invd = 1.f / fmaxf((float)dg, 1.f);
    mean_b[(size_t)n * 128 + l]      = __float2bfloat16(mean0 * invd);
    mean_b[(size_t)n * 128 + l + 64] = __float2bfloat16(mean1 * invd);
    #pragma unroll
    for (int h = 0; h < 4; ++h) {
        float it = 1.f / (s_t[h] + 1e-16f);
        xa[(size_t)n * 512 + h * 128 + l]      = __float2bfloat16(xaacc[h * 2] * it);
        xa[(size_t)n * 512 + h * 128 + l + 64] = __float2bfloat16(xaacc[h * 2 + 1] * it);
        float ig = 1.f / (s_g[h] + 1e-16f);
        ga[(size_t)n * 512 + h * 128 + l]      = __float2bfloat16(gaacc[h * 2] * ig);
        ga[(size_t)n * 512 + h * 128 + l + 64] = __float2bfloat16(gaacc[h * 2 + 1] * ig);
    }
    ea_b[(size_t)n * 64 + l] = __float2bfloat16(eaacc / (s_t[g4] + 1e-16f));
}

// ---------- fused tail (unchanged, proven ~90 us): depth-2 counted vmcnt DMA ----------
#define STASH(BIASP, USE_BV) do { \
    _Pragma("unroll") \
    for (int nt = 0; nt < 4; ++nt) { \
        int row_l = nt * 16 + lrow; \
        int sw = (row_l & 7) << 4; \
        float bvf = (USE_BV) ? ((deg_i[rA[nt]] > 0) ? 1.f : 0.f) : 0.f; \
        _Pragma("unroll") \
        for (int mt = 0; mt < 4; ++mt) { \
            int col = cbase + mt * 16 + quad * 4; \
            f32x4 bb = *(const f32x4*)((BIASP) + col); \
            u16x4 pk; \
            _Pragma("unroll") \
            for (int jj = 0; jj < 4; ++jj) { \
                float v = acc[mt][nt][jj] + bb[jj]; \
                if (USE_BV) v += bvf * bvsum[col + jj]; \
                bf16 h = __float2bfloat16(fmaxf(v, 0.f)); \
                pk[jj] = *(unsigned short*)&h; \
            } \
            *(u16x4*)(tileb + row_l * 256 + ((col * 2) ^ sw)) = pk; \
        } \
    } \
} while (0)

__global__ __launch_bounds__(128) void tail_fused(
    const bf16* __restrict__ mean_b, const bf16* __restrict__ x_b,
    const bf16* __restrict__ ga, const bf16* __restrict__ xa,
    const bf16* __restrict__ ea_b, const int* __restrict__ deg_i,
    const float* __restrict__ x,
    const bf16* __restrict__ Wt_sage, const bf16* __restrict__ Wgag,
    const bf16* __restrict__ Wt_cat, const bf16* __restrict__ Wt_fus,
    const float* __restrict__ sage_b, const float* __restrict__ gat_bias,
    const float* __restrict__ tskip_b, const float* __restrict__ bvsum,
    const float* __restrict__ fus_b, const float* __restrict__ fus_g,
    const float* __restrict__ fus_beta, const float* __restrict__ norm_g,
    const float* __restrict__ norm_b,
    float* __restrict__ out, int N)
{
    __shared__ __align__(16) char tileb[64 * 256];
    __shared__ __align__(16) short8 stg[2][2][8][64];
    __shared__ float2 st1[2][64];
    __shared__ float2 st2[2][64];
    int wave = threadIdx.x >> 6, lane = threadIdx.x & 63;
    int lrow = lane & 15, quad = lane >> 4;
    int kq = quad * 8;
    int row0 = blockIdx.x * 64;
    int cbase = wave * 64;
    int rA[4];
    #pragma unroll
    for (int t = 0; t < 4; ++t) {
        int r = row0 + t * 16 + lrow;
        rA[t] = r < N ? r : N - 1;
    }
    f32x4 facc[4][4] = {};

    auto issueA = [&](const bf16* base, int ldA, int kA, int par) {
        #pragma unroll
        for (int t = 0; t < 4; ++t)
            ld_lds16(&stg[wave][par][t][0], base + (size_t)rA[t] * ldA + kA);
    };
    auto issueW = [&](const bf16* Wt, int stepIdx, int par) {
        #pragma unroll
        for (int mt = 0; mt < 4; ++mt)
            ld_lds16(&stg[wave][par][4 + mt][0], Wt + ((size_t)(stepIdx * 4 + mt) * 64 + lane) * 8);
    };
    auto mfstep = [&](f32x4 (&acc)[4][4], int par) {
        short8 xf[4], wf[4];
        #pragma unroll
        for (int t = 0; t < 4; ++t) { xf[t] = stg[wave][par][t][lane]; wf[t] = stg[wave][par][4 + t][lane]; }
        #pragma unroll
        for (int mt = 0; mt < 4; ++mt)
            #pragma unroll
            for (int nt = 0; nt < 4; ++nt)
                acc[mt][nt] = __builtin_amdgcn_mfma_f32_16x16x32_bf16(wf[mt], xf[nt], acc[mt][nt], 0, 0, 0);
    };
    auto fuse_seg = [&](int SEG) {
        issueW(Wt_fus, wave * 12 + SEG * 4, 0);
        issueW(Wt_fus, wave * 12 + SEG * 4 + 1, 1);
        #pragma unroll
        for (int ks = 0; ks < 4; ++ks) {
            int cur = ks & 1;
            if (ks < 3) asm volatile("s_waitcnt vmcnt(4)" ::: "memory");
            else        asm volatile("s_waitcnt vmcnt(0)" ::: "memory");
            int kT = ks * 32 + kq;
            short8 xf[4], wf[4];
            #pragma unroll
            for (int t = 0; t < 4; ++t) {
                int row_l = t * 16 + lrow;
                xf[t] = *(const short8*)(tileb + row_l * 256 + ((kT * 2) ^ ((row_l & 7) << 4)));
            }
            #pragma unroll
            for (int mt = 0; mt < 4; ++mt) wf[mt] = stg[wave][cur][4 + mt][lane];
            #pragma unroll
            for (int mt = 0; mt < 4; ++mt)
                #pragma unroll
                for (int nt = 0; nt < 4; ++nt)
                    facc[mt][nt] = __builtin_amdgcn_mfma_f32_16x16x32_bf16(wf[mt], xf[nt], facc[mt][nt], 0, 0, 0);
            if (ks + 2 < 4) {
                asm volatile("s_waitcnt lgkmcnt(0)" ::: "memory");
                issueW(Wt_fus, wave * 12 + SEG * 4 + ks + 2, cur);
            }
        }
    };

    // ===== branch 1: SAGE  (K=256: mean_b | x_b, NS=8) =====
    {
        f32x4 acc[4][4] = {};
        issueA(mean_b, 128, kq, 0);
        issueW(Wt_sage, wave * 8, 0);
        issueA(mean_b, 128, 32 + kq, 1);
        issueW(Wt_sage, wave * 8 + 1, 1);
        #pragma unroll
        for (int ks = 0; ks < 8; ++ks) {
            int cur = ks & 1;
            if (ks < 7) asm volatile("s_waitcnt vmcnt(8)" ::: "memory");
            else        asm volatile("s_waitcnt vmcnt(0)" ::: "memory");
            mfstep(acc, cur);
            if (ks + 2 < 8) {
                asm volatile("s_waitcnt lgkmcnt(0)" ::: "memory");
                int p = ks + 2;
                issueA((p < 4) ? mean_b : x_b, 128, (p & 3) * 32 + kq, cur);
                issueW(Wt_sage, wave * 8 + p, cur);
            }
        }
        STASH(sage_b, 0);
    }
    __syncthreads();
    fuse_seg(0);
    __syncthreads();

    // ===== branch 2: cat  (K=704: xa | x_b | ea_b, NS=22) =====
    {
        f32x4 acc[4][4] = {};
        issueA(xa, 512, kq, 0);
        issueW(Wt_cat, wave * 22, 0);
        issueA(xa, 512, 32 + kq, 1);
        issueW(Wt_cat, wave * 22 + 1, 1);
        #pragma unroll
        for (int ks = 0; ks < 22; ++ks) {
            int cur = ks & 1;
            if (ks < 21) asm volatile("s_waitcnt vmcnt(8)" ::: "memory");
            else         asm volatile("s_waitcnt vmcnt(0)" ::: "memory");
            mfstep(acc, cur);
            if (ks + 2 < 22) {
                asm volatile("s_waitcnt lgkmcnt(0)" ::: "memory");
                int p = ks + 2;
                if (p < 16)      issueA(xa,   512, p * 32 + kq,        cur);
                else if (p < 20) issueA(x_b,  128, (p - 16) * 32 + kq, cur);
                else             issueA(ea_b,  64, (p - 20) * 32 + kq, cur);
                issueW(Wt_cat, wave * 22 + p, cur);
            }
        }
        STASH(tskip_b, 1);
    }
    __syncthreads();
    fuse_seg(1);
    __syncthreads();

    // ===== branch 3: GAT  (K=512: ga, NS=16) =====
    {
        f32x4 acc[4][4] = {};
        issueA(ga, 512, kq, 0);
        issueW(Wgag, wave * 16, 0);
        issueA(ga, 512, 32 + kq, 1);
        issueW(Wgag, wave * 16 + 1, 1);
        #pragma unroll
        for (int ks = 0; ks < 16; ++ks) {
            int cur = ks & 1;
            if (ks < 15) asm volatile("s_waitcnt vmcnt(8)" ::: "memory");
            else         asm volatile("s_waitcnt vmcnt(0)" ::: "memory");
            mfstep(acc, cur);
            if (ks + 2 < 16) {
                asm volatile("s_waitcnt lgkmcnt(0)" ::: "memory");
                int p = ks + 2;
                issueA(ga, 512, p * 32 + kq, cur);
                issueW(Wgag, wave * 16 + p, cur);
            }
        }
        STASH(gat_bias, 0);
    }
    __syncthreads();
    fuse_seg(2);

    // ===== epilogue: +fus_b -> LN1 -> relu -> +x -> LN2 -> out =====
    #pragma unroll
    for (int nt = 0; nt < 4; ++nt) {
        float s = 0.f, q = 0.f;
        #pragma unroll
        for (int mt = 0; mt < 4; ++mt) {
            int col = cbase + mt * 16 + quad * 4;
            f32x4 bb = *(const f32x4*)(fus_b + col);
            #pragma unroll
            for (int jj = 0; jj < 4; ++jj) {
                float v = facc[mt][nt][jj] + bb[jj];
                facc[mt][nt][jj] = v;
                s += v; q += v * v;
            }
        }
        s += __shfl_xor(s, 16, 64); q += __shfl_xor(q, 16, 64);
        s += __shfl_xor(s, 32, 64); q += __shfl_xor(q, 32, 64);
        if (quad == 0) st1[wave][nt * 16 + lrow] = make_float2(s, q);
    }
    __syncthreads();
    float m1[4], inv1[4];
    #pragma unroll
    for (int nt = 0; nt < 4; ++nt) {
        float2 a = st1[0][nt * 16 + lrow], b = st1[1][nt * 16 + lrow];
        float S = a.x + b.x, Q = a.y + b.y;
        float m = S * (1.f / 128.f);
        m1[nt] = m;
        inv1[nt] = rsqrtf(Q * (1.f / 128.f) - m * m + 1e-5f);
    }
    #pragma unroll
    for (int nt = 0; nt < 4; ++nt) {
        float s = 0.f, q = 0.f;
        #pragma unroll
        for (int mt = 0; mt < 4; ++mt) {
            int col = cbase + mt * 16 + quad * 4;
            f32x4 gv = *(const f32x4*)(fus_g + col);
            f32x4 bv = *(const f32x4*)(fus_beta + col);
            f32x4 xv = *(const f32x4*)(x + (size_t)rA[nt] * 128 + col);
            #pragma unroll
            for (int jj = 0; jj < 4; ++jj) {
                float y = fmaxf((facc[mt][nt][jj] - m1[nt]) * inv1[nt] * gv[jj] + bv[jj], 0.f);
                float z = xv[jj] + y;
                facc[mt][nt][jj] = z;
                s += z; q += z * z;
            }
        }
        s += __shfl_xor(s, 16, 64); q += __shfl_xor(q, 16, 64);
        s += __shfl_xor(s, 32, 64); q += __shfl_xor(q, 32, 64);
        if (quad == 0) st2[wave][nt * 16 + lrow] = make_float2(s, q);
    }
    __syncthreads();
    #pragma unroll
    for (int nt = 0; nt < 4; ++nt) {
        int row = row0 + nt * 16 + lrow;
        if (row >= N) continue;
        float2 a = st2[0][nt * 16 + lrow], b = st2[1][nt * 16 + lrow];
        float S = a.x + b.x, Q = a.y + b.y;
        float m = S * (1.f / 128.f);
        float inv = rsqrtf(Q * (1.f / 128.f) - m * m + 1e-5f);
        #pragma unroll
        for (int mt = 0; mt < 4; ++mt) {
            int col = cbase + mt * 16 + quad * 4;
            f32x4 ngv = *(const f32x4*)(norm_g + col);
            f32x4 nbv = *(const f32x4*)(norm_b + col);
            f32x4 o;
            #pragma unroll
            for (int jj = 0; jj < 4; ++jj)
                o[jj] = (facc[mt][nt][jj] - m) * inv * ngv[jj] + nbv[jj];
            *(f32x4*)(out + (size_t)row * 128 + col) = o;
        }
    }
}

extern "C" void kernel_launch(void* const* d_in, const int* in_sizes, int n_in,
                              void* d_out, int out_size, void* d_ws, size_t ws_size,
                              hipStream_t stream)
{
    const float* x        = (const float*)d_in[0];
    const int*   ei       = (const int*)d_in[1];
    const float* edge_attr= (const float*)d_in[2];
    const float* sage_Wl  = (const float*)d_in[3];
    const float* sage_Wr  = (const float*)d_in[4];
    const float* sage_b   = (const float*)d_in[5];
    const float* tq_W     = (const float*)d_in[6];
    const float* tq_b     = (const float*)d_in[7];
    const float* tk_W     = (const float*)d_in[8];
    const float* tk_b     = (const float*)d_in[9];
    const float* tv_W     = (const float*)d_in[10];
    const float* tv_b     = (const float*)d_in[11];
    const float* te_W     = (const float*)d_in[12];
    const float* tskip_W  = (const float*)d_in[13];
    const float* tskip_b  = (const float*)d_in[14];
    const float* gat_W    = (const float*)d_in[15];
    const float* att_s_w  = (const float*)d_in[16];
    const float* att_d_w  = (const float*)d_in[17];
    const float* gat_bias = (const float*)d_in[18];
    const float* gate_s   = (const float*)d_in[19];
    const float* gate_a   = (const float*)d_in[20];
    const float* gate_n   = (const float*)d_in[21];
    const float* fus_W    = (const float*)d_in[22];
    const float* fus_b    = (const float*)d_in[23];
    const float* fus_g    = (const float*)d_in[24];
    const float* fus_beta = (const float*)d_in[25];
    const float* norm_g   = (const float*)d_in[26];
    const float* norm_b   = (const float*)d_in[27];

    int N = in_sizes[0] / 128;
    int E = in_sizes[2] / 16;
    const int* src = ei;
    const int* dst = ei + E;
    int ND = N * 128;
    int nb = (N + 255) / 256;

    // ---- workspace ----
    char* wsb = (char*)d_ws;
    size_t off = 0;
    auto carve = [&](size_t bytes) -> char* {
        char* p = wsb + off;
        off += (bytes + 255) & ~(size_t)255;
        return p;
    };
    int*   deg_i   = (int*)carve((size_t)N * 4);          // zeroed by memset below
    int*   cnt2    = (int*)carve((size_t)N * 4);          // zeroed by memset below
    size_t zero_bytes = off;
    int*   loc     = (int*)carve((size_t)N * 4);
    int*   partial = (int*)carve((size_t)256 * 4);
    int*   col_src = (int*)carve((size_t)E * 4);
    int*   eidx    = (int*)carve((size_t)E * 4);
    bf16*  x_b     = (bf16*)carve((size_t)N * 128 * 2);
    bf16*  QT      = (bf16*)carve((size_t)N * 640 * 2);
    bf16*  xa      = (bf16*)carve((size_t)N * 512 * 2);
    bf16*  ga      = (bf16*)carve((size_t)N * 512 * 2);
    bf16*  mean_b  = (bf16*)carve((size_t)N * 128 * 2);
    bf16*  ea_b    = (bf16*)carve((size_t)N * 64 * 2);
    bf16*  Wbig    = (bf16*)carve((size_t)640 * 128 * 2);
    float* bbig    = (float*)carve((size_t)640 * 4);
    bf16*  Wt_sage = (bf16*)carve((size_t)128 * 256 * 2);
    bf16*  Wt_fus  = (bf16*)carve((size_t)128 * 384 * 2);
    bf16*  Wt_cat  = (bf16*)carve((size_t)128 * 704 * 2);
    bf16*  Wgag    = (bf16*)carve((size_t)128 * 512 * 2);
    float* bvsum   = (float*)carve((size_t)128 * 4);

    // 0) zero deg_i + cnt2 via async memset (stream-ordered, graph-capturable)
    hipMemsetAsync(wsb, 0, zero_bytes, stream);

    // 1) prep: x cast + ALL weight packs + Wbig/bbig + edge hist in ONE launch
    const long TP = 128 * 128;
    long prep_total = (long)(ND >> 3) + 5L * TP + 128L * 704 + 128L * 512 + 128
                    + 640L * 128 + (long)E;
    int prep_blocks = (int)((prep_total + 255) / 256);
    prep_all<<<prep_blocks, 256, 0, stream>>>(
        x, x_b, Wt_sage, sage_Wl, sage_Wr, Wt_fus, fus_W, gate_s, gate_a, gate_n,
        Wt_cat, tv_W, tskip_W, te_W, Wgag, gat_W, bvsum, tv_b,
        Wbig, bbig, tq_W, tk_W, tq_b, tk_b, att_s_w, att_d_w,
        dst, deg_i, E, ND);

    // 2) scan: parallel stage-1 + tiny stage-2 (rowptr computed on the fly by consumers)
    k_scan1<<<nb, 256, 0, stream>>>(deg_i, loc, partial, N);
    k_scan2<<<1, 256, 0, stream>>>(partial, nb);

    int gy64 = (N + 63) / 64, gnode = (N + 3) / 4;

    // 3) QT GEMM + edge scatter fused (independent work, one dispatch)
    gemm_scatter<<<gy64 + 256, 128, 0, stream>>>(
        x_b, Wbig, bbig, QT, N, 640,
        src, dst, loc, partial, cnt2, col_src, eidx, E, gy64);

    // 4) the one per-edge kernel
    node_fused<<<gnode, 256, 0, stream>>>(QT, x_b, edge_attr, loc, partial, deg_i,
                                          col_src, eidx, mean_b, xa, ga, ea_b, N);

    // 5) everything downstream of node_fused in ONE kernel (unchanged, proven)
    tail_fused<<<gy64, 128, 0, stream>>>(
        mean_b, x_b, ga, xa, ea_b, deg_i, x,
        Wt_sage, Wgag, Wt_cat, Wt_fus,
        sage_b, gat_bias, tskip_b, bvsum,
        fus_b, fus_g, fus_beta, norm_g, norm_b,
        (float*)d_out, N);
}

// Round 12
// 358.692 us; speedup vs baseline: 1.2280x; 1.0065x over previous
//
#include <hip/hip_runtime.h>
#include <hip/hip_bf16.h>

using bf16 = __hip_bfloat16;
typedef __attribute__((ext_vector_type(8))) short short8;
typedef __attribute__((ext_vector_type(4))) float f32x4;
typedef __attribute__((ext_vector_type(4))) unsigned short u16x4;

// ---------- helpers ----------
__device__ __forceinline__ void store4(bf16* p, float v0, float v1, float v2, float v3) {
    u16x4 pk;
    bf16 h0 = __float2bfloat16(v0); pk[0] = *(unsigned short*)&h0;
    bf16 h1 = __float2bfloat16(v1); pk[1] = *(unsigned short*)&h1;
    bf16 h2 = __float2bfloat16(v2); pk[2] = *(unsigned short*)&h2;
    bf16 h3 = __float2bfloat16(v3); pk[3] = *(unsigned short*)&h3;
    *(u16x4*)p = pk;
}
__device__ __forceinline__ float b2f(short s) { bf16 h; *(short*)&h = s; return __bfloat162float(h); }

// async global->LDS DMA, 16B per lane. LDS dst is wave-uniform base; HW adds lane*16.
__device__ __forceinline__ void ld_lds16(void* lds, const void* g) {
    __builtin_amdgcn_global_load_lds(
        (const __attribute__((address_space(1))) unsigned int*)g,
        (__attribute__((address_space(3))) unsigned int*)lds,
        16, 0, 0);
}

// Fragment-packed weight index: element (col c, k) stored so one MFMA wf load is
// 64 lanes x 16B CONTIGUOUS. layout: (((c64*(K/32)+ks)*4 + mt)*64 + lane)*8 + j.
__device__ __forceinline__ size_t pidx(int c, int k, int K) {
    return ((size_t)(((c >> 6) * (K >> 5) + (k >> 5)) * 4 + ((c >> 4) & 3)) * 64
            + (((k >> 3) & 3) * 16 + (c & 15))) * 8 + (k & 7);
}

// ---------- consolidated prep: x cast + ALL weight packs + Wbig/bbig + EDGE HIST, ONE launch ----------
// deg_i/cnt2 are zeroed by a preceding hipMemsetAsync (stream-ordered), so the hist
// segment's atomicAdds here are safe.
__global__ __launch_bounds__(256) void prep_all(
    const float* __restrict__ x, bf16* __restrict__ x_b,
    bf16* __restrict__ Wt_sage, const float* __restrict__ sage_Wl, const float* __restrict__ sage_Wr,
    bf16* __restrict__ Wt_fus, const float* __restrict__ fus_W,
    const float* __restrict__ gate_s, const float* __restrict__ gate_a, const float* __restrict__ gate_n,
    bf16* __restrict__ Wt_cat, const float* __restrict__ tvW,
    const float* __restrict__ tskipW, const float* __restrict__ teW,
    bf16* __restrict__ Wgag, const float* __restrict__ gatW,
    float* __restrict__ bvsum, const float* __restrict__ tvb,
    bf16* __restrict__ Wbig, float* __restrict__ bbig,
    const float* __restrict__ Wq, const float* __restrict__ Wk,
    const float* __restrict__ bq, const float* __restrict__ bk,
    const float* __restrict__ attS, const float* __restrict__ attD,
    const int* __restrict__ dst, int* __restrict__ deg_i, int E, int ND)
{
    const int TP = 128 * 128;
    long i = (long)blockIdx.x * 256 + threadIdx.x;
    long nv = ND >> 3;
    if (i < nv) {
        long b = i * 8;
        f32x4 a0 = *(const f32x4*)(x + b);
        f32x4 a1 = *(const f32x4*)(x + b + 4);
        short8 o;
        #pragma unroll
        for (int j = 0; j < 4; ++j) { bf16 h = __float2bfloat16(a0[j]); o[j] = *(short*)&h; }
        #pragma unroll
        for (int j = 0; j < 4; ++j) { bf16 h = __float2bfloat16(a1[j]); o[4 + j] = *(short*)&h; }
        *(short8*)(x_b + b) = o;
        return;
    }
    i -= nv;
    if (i < TP) { int k = (int)i / 128, c = (int)i % 128; Wt_sage[pidx(c, k, 256)] = __float2bfloat16(sage_Wl[i]); return; }
    i -= TP;
    if (i < TP) { int k = (int)i / 128, c = (int)i % 128; Wt_sage[pidx(c, k + 128, 256)] = __float2bfloat16(sage_Wr[i]); return; }
    i -= TP;
    if (i < 3 * TP) {
        int sseg = (int)(i / TP); int r = (int)(i % TP);
        int k = r / 128, c = r % 128;
        const float* g = sseg == 0 ? gate_s : (sseg == 1 ? gate_a : gate_n);
        float gv = 1.0f / (1.0f + expf(-g[0]));
        Wt_fus[pidx(c, sseg * 128 + k, 384)] = __float2bfloat16(fus_W[(size_t)sseg * TP + r] * gv);
        return;
    }
    i -= 3L * TP;
    if (i < 128L * 704) {
        int d = (int)(i / 704), kk = (int)(i % 704);
        float v;
        if (kk < 512)      { int h = kk >> 7, k = kk & 127; v = 0.25f * tvW[k * 512 + h * 128 + d]; }
        else if (kk < 640) { int k = kk - 512;              v = tskipW[k * 128 + d]; }
        else               { int t = kk - 640; int h = t >> 4, j = t & 15; v = 0.25f * teW[j * 512 + h * 128 + d]; }
        Wt_cat[pidx(d, kk, 704)] = __float2bfloat16(v);
        return;
    }
    i -= 128L * 704;
    if (i < 128L * 512) {
        int d = (int)i >> 9, k = (int)i & 511;
        int h = k >> 7, i2 = k & 127;
        Wgag[pidx(d, k, 512)] = __float2bfloat16(0.25f * gatW[(size_t)i2 * 512 + h * 128 + d]);
        return;
    }
    i -= 128L * 512;
    if (i < 128) {
        int d = (int)i;
        bvsum[d] = 0.25f * (tvb[d] + tvb[128 + d] + tvb[256 + d] + tvb[384 + d]);
        return;
    }
    i -= 128;
    if (i < 640L * 128) {
        // composed Wbig [640 cols][128 k] (fragment-packed) + bbig[640]
        int c = (int)(i >> 7), ip = (int)(i & 127);
        float acc = 0.f, bacc = 0.f;
        if (c < 512) {
            int h = c >> 7, i2 = c & 127;
            const float* wkrow = Wk + (size_t)i2 * 512 + h * 128;
            const float* wqrow = Wq + (size_t)ip * 512 + h * 128;
            for (int o = 0; o < 128; ++o) acc += wqrow[o] * wkrow[o];
            if (ip == 0) { const float* bqr = bq + h * 128; for (int o = 0; o < 128; ++o) bacc += bqr[o] * wkrow[o]; }
        } else if (c < 576) {
            int t = c - 512; int h = t >> 4, j = t & 15;
            const float* terow = teW + (size_t)j * 512 + h * 128;
            const float* wqrow = Wq + (size_t)ip * 512 + h * 128;
            for (int o = 0; o < 128; ++o) acc += wqrow[o] * terow[o];
            if (ip == 0) { const float* bqr = bq + h * 128; for (int o = 0; o < 128; ++o) bacc += bqr[o] * terow[o]; }
        } else if (c < 580) {
            int h = c - 576;
            const float* bkr = bk + h * 128;
            const float* wqrow = Wq + (size_t)ip * 512 + h * 128;
            for (int o = 0; o < 128; ++o) acc += wqrow[o] * bkr[o];
            if (ip == 0) { const float* bqr = bq + h * 128; for (int o = 0; o < 128; ++o) bacc += bqr[o] * bkr[o]; }
        } else if (c < 584) {
            int h = c - 580;
            const float* ar = attS + h * 128;
            const float* gr = gatW + (size_t)ip * 512 + h * 128;
            for (int d = 0; d < 128; ++d) acc += gr[d] * ar[d];
        } else if (c < 588) {
            int h = c - 584;
            const float* ar = attD + h * 128;
            const float* gr = gatW + (size_t)ip * 512 + h * 128;
            for (int d = 0; d < 128; ++d) acc += gr[d] * ar[d];
        }
        Wbig[pidx(c, ip, 128)] = __float2bfloat16(acc);
        if (ip == 0) bbig[c] = bacc;
        return;
    }
    i -= 640L * 128;
    // edge histogram (replaces the k_hist dispatch)
    if (i < E) atomicAdd(&deg_i[dst[i]], 1);
}

// ---------- scan stage 1: per-block exclusive prefix (loc) + block sums (partial) ----------
__global__ __launch_bounds__(256) void k_scan1(
    const int* __restrict__ deg_i, int* __restrict__ loc, int* __restrict__ partial, int N)
{
    __shared__ int sm[256];
    int t = threadIdx.x, i = blockIdx.x * 256 + t;
    int v = (i < N) ? deg_i[i] : 0;
    sm[t] = v;
    __syncthreads();
    for (int off = 1; off < 256; off <<= 1) {
        int add = (t >= off) ? sm[t - off] : 0;
        __syncthreads();
        sm[t] += add;
        __syncthreads();
    }
    if (i < N) loc[i] = sm[t] - v;
    if (t == 255) partial[blockIdx.x] = sm[255];
}

// ---------- scan stage 2: exclusive scan of block sums (carry loop handles any nb) ----------
__global__ __launch_bounds__(256) void k_scan2(int* __restrict__ partial, int nb) {
    __shared__ int sm[256];
    int t = threadIdx.x;
    int carry = 0;
    for (int base = 0; base < nb; base += 256) {
        int idx = base + t;
        int v = (idx < nb) ? partial[idx] : 0;
        sm[t] = v;
        __syncthreads();
        for (int off = 1; off < 256; off <<= 1) {
            int add = (t >= off) ? sm[t - off] : 0;
            __syncthreads();
            sm[t] += add;
            __syncthreads();
        }
        if (idx < nb) partial[idx] = carry + sm[t] - v;
        int tot = sm[255];
        __syncthreads();
        carry += tot;
    }
}
// NOTE: scan3 is GONE -- consumers compute rowptr on the fly: loc[d] + partial[d>>8].

// ---------- gemm_wide + edge scatter fused in one dispatch (independent work) ----------
__global__ __launch_bounds__(128) void gemm_scatter(
    const bf16* __restrict__ A, const bf16* __restrict__ Wt,
    const float* __restrict__ bias, bf16* __restrict__ C, int n_rows, int ldc,
    const int* __restrict__ src, const int* __restrict__ dst,
    const int* __restrict__ loc, const int* __restrict__ partial, int* __restrict__ cnt2,
    int* __restrict__ col_src, int* __restrict__ eidx, int E, int gy)
{
    __shared__ __align__(16) short8 wstg[2][2][4][64];   // [wave][parity][mt][lane] = 16KB
    if (blockIdx.x >= gy) {
        int e0 = (blockIdx.x - gy) * 128 + threadIdx.x;
        int stride = (gridDim.x - gy) * 128;
        for (int e = e0; e < E; e += stride) {
            int d = dst[e];
            int pos = loc[d] + partial[d >> 8] + atomicAdd(&cnt2[d], 1);
            col_src[pos] = src[e];
            eidx[pos] = e;
        }
        return;
    }
    int row0 = blockIdx.x * 64;
    int wave = threadIdx.x >> 6, lane = threadIdx.x & 63;
    int lrow = lane & 15, quad = lane >> 4;
    short8 xb[4][4];
    #pragma unroll
    for (int ks = 0; ks < 4; ++ks)
        #pragma unroll
        for (int nt = 0; nt < 4; ++nt) {
            int r = row0 + nt * 16 + lrow;
            r = r < n_rows ? r : n_rows - 1;
            xb[ks][nt] = *(const short8*)(A + (size_t)r * 128 + ks * 32 + quad * 8);
        }
    auto issueW = [&](int s, int par) {
        int c64 = (s >> 2) * 2 + wave, ks = s & 3;
        #pragma unroll
        for (int mt = 0; mt < 4; ++mt)
            ld_lds16(&wstg[wave][par][mt][0], Wt + ((size_t)((c64 * 4 + ks) * 4 + mt) * 64 + lane) * 8);
    };
    issueW(0, 0);
    issueW(1, 1);
    for (int cy = 0; cy < 5; ++cy) {
        f32x4 acc[4][4] = {};
        #pragma unroll
        for (int ks = 0; ks < 4; ++ks) {
            int s = cy * 4 + ks, par = s & 1;
            if (s < 18) asm volatile("s_waitcnt vmcnt(4)" ::: "memory");
            else        asm volatile("s_waitcnt vmcnt(0)" ::: "memory");
            short8 wf[4];
            #pragma unroll
            for (int mt = 0; mt < 4; ++mt) wf[mt] = wstg[wave][par][mt][lane];
            asm volatile("s_waitcnt lgkmcnt(0)" ::: "memory");
            if (s + 2 < 20) issueW(s + 2, par);
            __builtin_amdgcn_sched_barrier(0);
            #pragma unroll
            for (int mt = 0; mt < 4; ++mt)
                #pragma unroll
                for (int nt = 0; nt < 4; ++nt)
                    acc[mt][nt] = __builtin_amdgcn_mfma_f32_16x16x32_bf16(wf[mt], xb[ks][nt], acc[mt][nt], 0, 0, 0);
        }
        int cbase = (cy * 2 + wave) * 64;
        #pragma unroll
        for (int nt = 0; nt < 4; ++nt) {
            int row = row0 + nt * 16 + lrow;
            if (row >= n_rows) continue;
            #pragma unroll
            for (int mt = 0; mt < 4; ++mt) {
                int col = cbase + mt * 16 + quad * 4;
                float b0 = bias[col], b1 = bias[col + 1], b2 = bias[col + 2], b3 = bias[col + 3];
                store4(&C[(size_t)row * ldc + col],
                       acc[mt][nt][0] + b0, acc[mt][nt][1] + b1,
                       acc[mt][nt][2] + b2, acc[mt][nt][3] + b3);
            }
        }
    }
}

// ---------- node_fused: SAGE mean + transformer attn + GAT attn, softmax WITHOUT max-shift ----------
#define NCAP 8
__global__ __launch_bounds__(256) void node_fused(
    const bf16* __restrict__ QT, const bf16* __restrict__ x_b,
    const float* __restrict__ edge_attr,
    const int* __restrict__ loc, const int* __restrict__ partial,
    const int* __restrict__ deg_i,
    const int* __restrict__ col_src, const int* __restrict__ eidx,
    bf16* __restrict__ mean_b, bf16* __restrict__ xa, bf16* __restrict__ ga,
    bf16* __restrict__ ea_b, int N)
{
    __shared__ short8 xS[4][NCAP][16];
    __shared__ float eaS[4][NCAP][16];
    __shared__ float wTs[4][NCAP][4];
    __shared__ float wGs[4][NCAP][4];
    int w = threadIdx.x >> 6, l = threadIdx.x & 63;
    int n = blockIdx.x * 4 + w;
    if (n >= N) return;
    int j = l & 15, g4 = l >> 4;
    int p0 = loc[n] + partial[n >> 8], dg = deg_i[n];
    const float scale = 0.08838834764831845f;
    float qtF[4][8], qeqL[4], qbL[4], adh[4], ashn[4];
    #pragma unroll
    for (int h = 0; h < 4; ++h) {
        short8 q = *(const short8*)(QT + (size_t)n * 640 + h * 128 + j * 8);
        #pragma unroll
        for (int t = 0; t < 8; ++t) qtF[h][t] = b2f(q[t]);
        qeqL[h] = __bfloat162float(QT[(size_t)n * 640 + 512 + h * 16 + j]);
        qbL[h]  = __bfloat162float(QT[(size_t)n * 640 + 576 + h]);
        ashn[h] = __bfloat162float(QT[(size_t)n * 640 + 580 + h]);
        adh[h]  = __bfloat162float(QT[(size_t)n * 640 + 584 + h]);
    }
    float xn0 = __bfloat162float(x_b[(size_t)n * 128 + l]);
    float xn1 = __bfloat162float(x_b[(size_t)n * 128 + l + 64]);
    float s_t[4], s_g[4], xaacc[8] = {}, gaacc[8];
    float mean0 = 0.f, mean1 = 0.f, eaacc = 0.f;
    #pragma unroll
    for (int h = 0; h < 4; ++h) {
        s_t[h] = 0.f;
        float lgs = ashn[h] + adh[h];
        lgs = lgs > 0.f ? lgs : 0.2f * lgs;
        float e = __expf(lgs);
        s_g[h] = e;
        gaacc[h * 2] = e * xn0; gaacc[h * 2 + 1] = e * xn1;
    }
    for (int c0 = 0; c0 < dg; c0 += NCAP) {
        int cc = min(NCAP, dg - c0);
        for (int it = 0; it < ((cc + 3) >> 2); ++it) {
            int i = it * 4 + g4;
            bool valid = i < cc;
            int s = 0;
            short8 xf = {0, 0, 0, 0, 0, 0, 0, 0};
            float ea_j = 0.f;
            if (valid) {
                s = col_src[p0 + c0 + i];
                int eg = eidx[p0 + c0 + i];
                xf = *(const short8*)(x_b + (size_t)s * 128 + j * 8);
                ea_j = edge_attr[(size_t)eg * 16 + j];
                xS[w][i][j] = xf;
                eaS[w][i][j] = ea_j;
            }
            float xv[8];
            #pragma unroll
            for (int t = 0; t < 8; ++t) xv[t] = b2f(xf[t]);
            float p[4];
            #pragma unroll
            for (int h = 0; h < 4; ++h) {
                float a = ea_j * qeqL[h];
                #pragma unroll
                for (int t = 0; t < 8; ++t) a += xv[t] * qtF[h][t];
                p[h] = a;
            }
            #pragma unroll
            for (int off = 1; off < 16; off <<= 1)
                #pragma unroll
                for (int h = 0; h < 4; ++h)
                    p[h] += __shfl_xor(p[h], off, 64);
            if (valid && j == 0) {
                #pragma unroll
                for (int h = 0; h < 4; ++h) {
                    wTs[w][i][h] = __expf((p[h] + qbL[h]) * scale);
                    float as_s = __bfloat162float(QT[(size_t)s * 640 + 580 + h]);
                    float lg = as_s + adh[h];
                    lg = lg > 0.f ? lg : 0.2f * lg;
                    wGs[w][i][h] = __expf(lg);
                }
            }
        }
        for (int i = 0; i < cc; ++i) {
            const bf16* xr = (const bf16*)&xS[w][i][0];
            float xv0 = __bfloat162float(xr[l]);
            float xv1 = __bfloat162float(xr[l + 64]);
            mean0 += xv0; mean1 += xv1;
            #pragma unroll
            for (int h = 0; h < 4; ++h) {
                float at = wTs[w][i][h], ag = wGs[w][i][h];
                s_t[h] += at; s_g[h] += ag;
                xaacc[h * 2] += at * xv0; xaacc[h * 2 + 1] += at * xv1;
                gaacc[h * 2] += ag * xv0; gaacc[h * 2 + 1] += ag * xv1;
            }
            eaacc += wTs[w][i][g4] * eaS[w][i][j];
        }
    }
    float invd = 1.f / fmaxf((float)dg, 1.f);
    mean_b[(size_t)n * 128 + l]      = __float2bfloat16(mean0 * invd);
    mean_b[(size_t)n * 128 + l + 64] = __float2bfloat16(mean1 * invd);
    #pragma unroll
    for (int h = 0; h < 4; ++h) {
        float it = 1.f / (s_t[h] + 1e-16f);
        xa[(size_t)n * 512 + h * 128 + l]      = __float2bfloat16(xaacc[h * 2] * it);
        xa[(size_t)n * 512 + h * 128 + l + 64] = __float2bfloat16(xaacc[h * 2 + 1] * it);
        float ig = 1.f / (s_g[h] + 1e-16f);
        ga[(size_t)n * 512 + h * 128 + l]      = __float2bfloat16(gaacc[h * 2] * ig);
        ga[(size_t)n * 512 + h * 128 + l + 64] = __float2bfloat16(gaacc[h * 2 + 1] * ig);
    }
    ea_b[(size_t)n * 64 + l] = __float2bfloat16(eaacc / (s_t[g4] + 1e-16f));
}

// ---------- fused tail v8: v7 + cross-phase prefetch (no cold restarts at phase entry) ----------
// After each STASH the wave's A- and W-staging slots are provably idle (all ds_reads retired
// before the preceding MFMAs issued), so we issue the NEXT phase's first two load-groups there:
// fuse W0/W1 always, plus next-branch A0/A1 when one exists. fuse_seg no longer issues at entry.
// Branches 2/3 prologue is W-only with first wait vmcnt(4) (A already resident). Extra in-flight
// loads only make waits more conservative -- never under-synchronized.
#define STASH(BIASP, USE_BV) do { \
    _Pragma("unroll") \
    for (int nt = 0; nt < 4; ++nt) { \
        int row_l = nt * 16 + lrow; \
        int sw = (row_l & 7) << 4; \
        float bvf = (USE_BV) ? ((deg_i[rA[nt]] > 0) ? 1.f : 0.f) : 0.f; \
        _Pragma("unroll") \
        for (int mt = 0; mt < 4; ++mt) { \
            int col = cbase + mt * 16 + quad * 4; \
            f32x4 bb = *(const f32x4*)((BIASP) + col); \
            u16x4 pk; \
            _Pragma("unroll") \
            for (int jj = 0; jj < 4; ++jj) { \
                float v = acc[mt][nt][jj] + bb[jj]; \
                if (USE_BV) v += bvf * bvsum[col + jj]; \
                bf16 h = __float2bfloat16(fmaxf(v, 0.f)); \
                pk[jj] = *(unsigned short*)&h; \
            } \
            *(u16x4*)(tileb + row_l * 256 + ((col * 2) ^ sw)) = pk; \
        } \
    } \
} while (0)

__global__ __launch_bounds__(128) void tail_fused(
    const bf16* __restrict__ mean_b, const bf16* __restrict__ x_b,
    const bf16* __restrict__ ga, const bf16* __restrict__ xa,
    const bf16* __restrict__ ea_b, const int* __restrict__ deg_i,
    const float* __restrict__ x,
    const bf16* __restrict__ Wt_sage, const bf16* __restrict__ Wgag,
    const bf16* __restrict__ Wt_cat, const bf16* __restrict__ Wt_fus,
    const float* __restrict__ sage_b, const float* __restrict__ gat_bias,
    const float* __restrict__ tskip_b, const float* __restrict__ bvsum,
    const float* __restrict__ fus_b, const float* __restrict__ fus_g,
    const float* __restrict__ fus_beta, const float* __restrict__ norm_g,
    const float* __restrict__ norm_b,
    float* __restrict__ out, int N)
{
    __shared__ __align__(16) char tileb[64 * 256];
    __shared__ __align__(16) short8 stg[2][2][8][64];
    __shared__ float2 st1[2][64];
    __shared__ float2 st2[2][64];
    int wave = threadIdx.x >> 6, lane = threadIdx.x & 63;
    int lrow = lane & 15, quad = lane >> 4;
    int kq = quad * 8;
    int row0 = blockIdx.x * 64;
    int cbase = wave * 64;
    int rA[4];
    #pragma unroll
    for (int t = 0; t < 4; ++t) {
        int r = row0 + t * 16 + lrow;
        rA[t] = r < N ? r : N - 1;
    }
    f32x4 facc[4][4] = {};

    auto issueA = [&](const bf16* base, int ldA, int kA, int par) {
        #pragma unroll
        for (int t = 0; t < 4; ++t)
            ld_lds16(&stg[wave][par][t][0], base + (size_t)rA[t] * ldA + kA);
    };
    auto issueW = [&](const bf16* Wt, int stepIdx, int par) {
        #pragma unroll
        for (int mt = 0; mt < 4; ++mt)
            ld_lds16(&stg[wave][par][4 + mt][0], Wt + ((size_t)(stepIdx * 4 + mt) * 64 + lane) * 8);
    };
    auto mfstep = [&](f32x4 (&acc)[4][4], int par) {
        short8 xf[4], wf[4];
        #pragma unroll
        for (int t = 0; t < 4; ++t) { xf[t] = stg[wave][par][t][lane]; wf[t] = stg[wave][par][4 + t][lane]; }
        #pragma unroll
        for (int mt = 0; mt < 4; ++mt)
            #pragma unroll
            for (int nt = 0; nt < 4; ++nt)
                acc[mt][nt] = __builtin_amdgcn_mfma_f32_16x16x32_bf16(wf[mt], xf[nt], acc[mt][nt], 0, 0, 0);
    };
    // fuse segment: W0/W1 already in flight (pre-issued after the preceding STASH)
    auto fuse_seg = [&](int SEG) {
        #pragma unroll
        for (int ks = 0; ks < 4; ++ks) {
            int cur = ks & 1;
            if (ks < 3) asm volatile("s_waitcnt vmcnt(4)" ::: "memory");
            else        asm volatile("s_waitcnt vmcnt(0)" ::: "memory");
            int kT = ks * 32 + kq;
            short8 xf[4], wf[4];
            #pragma unroll
            for (int t = 0; t < 4; ++t) {
                int row_l = t * 16 + lrow;
                xf[t] = *(const short8*)(tileb + row_l * 256 + ((kT * 2) ^ ((row_l & 7) << 4)));
            }
            #pragma unroll
            for (int mt = 0; mt < 4; ++mt) wf[mt] = stg[wave][cur][4 + mt][lane];
            #pragma unroll
            for (int mt = 0; mt < 4; ++mt)
                #pragma unroll
                for (int nt = 0; nt < 4; ++nt)
                    facc[mt][nt] = __builtin_amdgcn_mfma_f32_16x16x32_bf16(wf[mt], xf[nt], facc[mt][nt], 0, 0, 0);
            if (ks + 2 < 4) {
                asm volatile("s_waitcnt lgkmcnt(0)" ::: "memory");
                issueW(Wt_fus, wave * 12 + SEG * 4 + ks + 2, cur);
            }
        }
    };

    // ===== branch 1: SAGE  (K=256: mean_b | x_b, NS=8) =====
    {
        f32x4 acc[4][4] = {};
        issueA(mean_b, 128, kq, 0);
        issueW(Wt_sage, wave * 8, 0);
        issueA(mean_b, 128, 32 + kq, 1);
        issueW(Wt_sage, wave * 8 + 1, 1);
        #pragma unroll
        for (int ks = 0; ks < 8; ++ks) {
            int cur = ks & 1;
            if (ks < 7) asm volatile("s_waitcnt vmcnt(8)" ::: "memory");
            else        asm volatile("s_waitcnt vmcnt(0)" ::: "memory");
            mfstep(acc, cur);
            if (ks + 2 < 8) {
                asm volatile("s_waitcnt lgkmcnt(0)" ::: "memory");
                int p = ks + 2;
                issueA((p < 4) ? mean_b : x_b, 128, (p & 3) * 32 + kq, cur);
                issueW(Wt_sage, wave * 8 + p, cur);
            }
        }
        STASH(sage_b, 0);
        // prefetch: branch-2 A steps 0,1 + fuse-0 W steps 0,1 (slots idle; ds ops drained)
        asm volatile("s_waitcnt lgkmcnt(0)" ::: "memory");
        issueA(xa, 512, kq, 0);
        issueA(xa, 512, 32 + kq, 1);
        issueW(Wt_fus, wave * 12 + 0, 0);
        issueW(Wt_fus, wave * 12 + 1, 1);
    }
    __syncthreads();
    fuse_seg(0);
    __syncthreads();

    // ===== branch 2: cat  (K=704: xa | x_b | ea_b, NS=22; A0/A1 prefetched) =====
    {
        f32x4 acc[4][4] = {};
        issueW(Wt_cat, wave * 22, 0);
        issueW(Wt_cat, wave * 22 + 1, 1);
        #pragma unroll
        for (int ks = 0; ks < 22; ++ks) {
            int cur = ks & 1;
            if (ks == 0)      asm volatile("s_waitcnt vmcnt(4)" ::: "memory");
            else if (ks < 21) asm volatile("s_waitcnt vmcnt(8)" ::: "memory");
            else              asm volatile("s_waitcnt vmcnt(0)" ::: "memory");
            mfstep(acc, cur);
            if (ks + 2 < 22) {
                asm volatile("s_waitcnt lgkmcnt(0)" ::: "memory");
                int p = ks + 2;
                if (p < 16)      issueA(xa,   512, p * 32 + kq,        cur);
                else if (p < 20) issueA(x_b,  128, (p - 16) * 32 + kq, cur);
                else             issueA(ea_b,  64, (p - 20) * 32 + kq, cur);
                issueW(Wt_cat, wave * 22 + p, cur);
            }
        }
        STASH(tskip_b, 1);
        // prefetch: branch-3 A steps 0,1 + fuse-1 W steps 0,1
        asm volatile("s_waitcnt lgkmcnt(0)" ::: "memory");
        issueA(ga, 512, kq, 0);
        issueA(ga, 512, 32 + kq, 1);
        issueW(Wt_fus, wave * 12 + 4, 0);
        issueW(Wt_fus, wave * 12 + 5, 1);
    }
    __syncthreads();
    fuse_seg(1);
    __syncthreads();

    // ===== branch 3: GAT  (K=512: ga, NS=16; A0/A1 prefetched) =====
    {
        f32x4 acc[4][4] = {};
        issueW(Wgag, wave * 16, 0);
        issueW(Wgag, wave * 16 + 1, 1);
        #pragma unroll
        for (int ks = 0; ks < 16; ++ks) {
            int cur = ks & 1;
            if (ks == 0)      asm volatile("s_waitcnt vmcnt(4)" ::: "memory");
            else if (ks < 15) asm volatile("s_waitcnt vmcnt(8)" ::: "memory");
            else              asm volatile("s_waitcnt vmcnt(0)" ::: "memory");
            mfstep(acc, cur);
            if (ks + 2 < 16) {
                asm volatile("s_waitcnt lgkmcnt(0)" ::: "memory");
                int p = ks + 2;
                issueA(ga, 512, p * 32 + kq, cur);
                issueW(Wgag, wave * 16 + p, cur);
            }
        }
        STASH(gat_bias, 0);
        // prefetch: fuse-2 W steps 0,1 (no next branch)
        asm volatile("s_waitcnt lgkmcnt(0)" ::: "memory");
        issueW(Wt_fus, wave * 12 + 8, 0);
        issueW(Wt_fus, wave * 12 + 9, 1);
    }
    __syncthreads();
    fuse_seg(2);

    // ===== epilogue: +fus_b -> LN1 -> relu -> +x -> LN2 -> out =====
    #pragma unroll
    for (int nt = 0; nt < 4; ++nt) {
        float s = 0.f, q = 0.f;
        #pragma unroll
        for (int mt = 0; mt < 4; ++mt) {
            int col = cbase + mt * 16 + quad * 4;
            f32x4 bb = *(const f32x4*)(fus_b + col);
            #pragma unroll
            for (int jj = 0; jj < 4; ++jj) {
                float v = facc[mt][nt][jj] + bb[jj];
                facc[mt][nt][jj] = v;
                s += v; q += v * v;
            }
        }
        s += __shfl_xor(s, 16, 64); q += __shfl_xor(q, 16, 64);
        s += __shfl_xor(s, 32, 64); q += __shfl_xor(q, 32, 64);
        if (quad == 0) st1[wave][nt * 16 + lrow] = make_float2(s, q);
    }
    __syncthreads();
    float m1[4], inv1[4];
    #pragma unroll
    for (int nt = 0; nt < 4; ++nt) {
        float2 a = st1[0][nt * 16 + lrow], b = st1[1][nt * 16 + lrow];
        float S = a.x + b.x, Q = a.y + b.y;
        float m = S * (1.f / 128.f);
        m1[nt] = m;
        inv1[nt] = rsqrtf(Q * (1.f / 128.f) - m * m + 1e-5f);
    }
    #pragma unroll
    for (int nt = 0; nt < 4; ++nt) {
        float s = 0.f, q = 0.f;
        #pragma unroll
        for (int mt = 0; mt < 4; ++mt) {
            int col = cbase + mt * 16 + quad * 4;
            f32x4 gv = *(const f32x4*)(fus_g + col);
            f32x4 bv = *(const f32x4*)(fus_beta + col);
            f32x4 xv = *(const f32x4*)(x + (size_t)rA[nt] * 128 + col);
            #pragma unroll
            for (int jj = 0; jj < 4; ++jj) {
                float y = fmaxf((facc[mt][nt][jj] - m1[nt]) * inv1[nt] * gv[jj] + bv[jj], 0.f);
                float z = xv[jj] + y;
                facc[mt][nt][jj] = z;
                s += z; q += z * z;
            }
        }
        s += __shfl_xor(s, 16, 64); q += __shfl_xor(q, 16, 64);
        s += __shfl_xor(s, 32, 64); q += __shfl_xor(q, 32, 64);
        if (quad == 0) st2[wave][nt * 16 + lrow] = make_float2(s, q);
    }
    __syncthreads();
    #pragma unroll
    for (int nt = 0; nt < 4; ++nt) {
        int row = row0 + nt * 16 + lrow;
        if (row >= N) continue;
        float2 a = st2[0][nt * 16 + lrow], b = st2[1][nt * 16 + lrow];
        float S = a.x + b.x, Q = a.y + b.y;
        float m = S * (1.f / 128.f);
        float inv = rsqrtf(Q * (1.f / 128.f) - m * m + 1e-5f);
        #pragma unroll
        for (int mt = 0; mt < 4; ++mt) {
            int col = cbase + mt * 16 + quad * 4;
            f32x4 ngv = *(const f32x4*)(norm_g + col);
            f32x4 nbv = *(const f32x4*)(norm_b + col);
            f32x4 o;
            #pragma unroll
            for (int jj = 0; jj < 4; ++jj)
                o[jj] = (facc[mt][nt][jj] - m) * inv * ngv[jj] + nbv[jj];
            *(f32x4*)(out + (size_t)row * 128 + col) = o;
        }
    }
}

extern "C" void kernel_launch(void* const* d_in, const int* in_sizes, int n_in,
                              void* d_out, int out_size, void* d_ws, size_t ws_size,
                              hipStream_t stream)
{
    const float* x        = (const float*)d_in[0];
    const int*   ei       = (const int*)d_in[1];
    const float* edge_attr= (const float*)d_in[2];
    const float* sage_Wl  = (const float*)d_in[3];
    const float* sage_Wr  = (const float*)d_in[4];
    const float* sage_b   = (const float*)d_in[5];
    const float* tq_W     = (const float*)d_in[6];
    const float* tq_b     = (const float*)d_in[7];
    const float* tk_W     = (const float*)d_in[8];
    const float* tk_b     = (const float*)d_in[9];
    const float* tv_W     = (const float*)d_in[10];
    const float* tv_b     = (const float*)d_in[11];
    const float* te_W     = (const float*)d_in[12];
    const float* tskip_W  = (const float*)d_in[13];
    const float* tskip_b  = (const float*)d_in[14];
    const float* gat_W    = (const float*)d_in[15];
    const float* att_s_w  = (const float*)d_in[16];
    const float* att_d_w  = (const float*)d_in[17];
    const float* gat_bias = (const float*)d_in[18];
    const float* gate_s   = (const float*)d_in[19];
    const float* gate_a   = (const float*)d_in[20];
    const float* gate_n   = (const float*)d_in[21];
    const float* fus_W    = (const float*)d_in[22];
    const float* fus_b    = (const float*)d_in[23];
    const float* fus_g    = (const float*)d_in[24];
    const float* fus_beta = (const float*)d_in[25];
    const float* norm_g   = (const float*)d_in[26];
    const float* norm_b   = (const float*)d_in[27];

    int N = in_sizes[0] / 128;
    int E = in_sizes[2] / 16;
    const int* src = ei;
    const int* dst = ei + E;
    int ND = N * 128;
    int nb = (N + 255) / 256;

    // ---- workspace ----
    char* wsb = (char*)d_ws;
    size_t off = 0;
    auto carve = [&](size_t bytes) -> char* {
        char* p = wsb + off;
        off += (bytes + 255) & ~(size_t)255;
        return p;
    };
    int*   deg_i   = (int*)carve((size_t)N * 4);          // zeroed by memset below
    int*   cnt2    = (int*)carve((size_t)N * 4);          // zeroed by memset below
    size_t zero_bytes = off;
    int*   loc     = (int*)carve((size_t)N * 4);
    int*   partial = (int*)carve((size_t)256 * 4);
    int*   col_src = (int*)carve((size_t)E * 4);
    int*   eidx    = (int*)carve((size_t)E * 4);
    bf16*  x_b     = (bf16*)carve((size_t)N * 128 * 2);
    bf16*  QT      = (bf16*)carve((size_t)N * 640 * 2);
    bf16*  xa      = (bf16*)carve((size_t)N * 512 * 2);
    bf16*  ga      = (bf16*)carve((size_t)N * 512 * 2);
    bf16*  mean_b  = (bf16*)carve((size_t)N * 128 * 2);
    bf16*  ea_b    = (bf16*)carve((size_t)N * 64 * 2);
    bf16*  Wbig    = (bf16*)carve((size_t)640 * 128 * 2);
    float* bbig    = (float*)carve((size_t)640 * 4);
    bf16*  Wt_sage = (bf16*)carve((size_t)128 * 256 * 2);
    bf16*  Wt_fus  = (bf16*)carve((size_t)128 * 384 * 2);
    bf16*  Wt_cat  = (bf16*)carve((size_t)128 * 704 * 2);
    bf16*  Wgag    = (bf16*)carve((size_t)128 * 512 * 2);
    float* bvsum   = (float*)carve((size_t)128 * 4);

    // 0) zero deg_i + cnt2 via async memset (stream-ordered, graph-capturable)
    hipMemsetAsync(wsb, 0, zero_bytes, stream);

    // 1) prep: x cast + ALL weight packs + Wbig/bbig + edge hist in ONE launch
    const long TP = 128 * 128;
    long prep_total = (long)(ND >> 3) + 5L * TP + 128L * 704 + 128L * 512 + 128
                    + 640L * 128 + (long)E;
    int prep_blocks = (int)((prep_total + 255) / 256);
    prep_all<<<prep_blocks, 256, 0, stream>>>(
        x, x_b, Wt_sage, sage_Wl, sage_Wr, Wt_fus, fus_W, gate_s, gate_a, gate_n,
        Wt_cat, tv_W, tskip_W, te_W, Wgag, gat_W, bvsum, tv_b,
        Wbig, bbig, tq_W, tk_W, tq_b, tk_b, att_s_w, att_d_w,
        dst, deg_i, E, ND);

    // 2) scan: parallel stage-1 + tiny stage-2 (rowptr computed on the fly by consumers)
    k_scan1<<<nb, 256, 0, stream>>>(deg_i, loc, partial, N);
    k_scan2<<<1, 256, 0, stream>>>(partial, nb);

    int gy64 = (N + 63) / 64, gnode = (N + 3) / 4;

    // 3) QT GEMM + edge scatter fused (independent work, one dispatch)
    gemm_scatter<<<gy64 + 256, 128, 0, stream>>>(
        x_b, Wbig, bbig, QT, N, 640,
        src, dst, loc, partial, cnt2, col_src, eidx, E, gy64);

    // 4) the one per-edge kernel
    node_fused<<<gnode, 256, 0, stream>>>(QT, x_b, edge_attr, loc, partial, deg_i,
                                          col_src, eidx, mean_b, xa, ga, ea_b, N);

    // 5) everything downstream of node_fused in ONE kernel (cross-phase prefetch)
    tail_fused<<<gy64, 128, 0, stream>>>(
        mean_b, x_b, ga, xa, ea_b, deg_i, x,
        Wt_sage, Wgag, Wt_cat, Wt_fus,
        sage_b, gat_bias, tskip_b, bvsum,
        fus_b, fus_g, fus_beta, norm_g, norm_b,
        (float*)d_out, N);
}